// Round 4
// baseline (22013.853 us; speedup 1.0000x reference)
//
#include <hip/hip_runtime.h>
#include <cstdio>
#include <cstddef>

#define BB 128
#define SS 512
#define HH 128
#define NG 2048   // 4H*4 components, permuted column layout n' = m*16 + g*4 + co
#define NBLK 256

typedef unsigned short u16;
typedef __attribute__((ext_vector_type(8))) u16   u16x8;
typedef __attribute__((ext_vector_type(8))) short s16x8;
typedef __attribute__((ext_vector_type(4))) float f32x4;

__constant__ int   c_widx[16] = {0,1,2,3, 1,0,3,2, 2,3,0,1, 3,2,1,0};
__constant__ float c_sgn [16] = {1.f,1.f,1.f,1.f, -1.f,1.f,-1.f,1.f,
                                 -1.f,1.f,1.f,-1.f, -1.f,-1.f,1.f,1.f};

__device__ __forceinline__ float fsig(float x) { return 1.f/(1.f + __expf(-x)); }
__device__ __forceinline__ float ftanh(float x) {
  float ax = fabsf(x);
  float e  = __expf(-2.f*ax);
  float tt = (1.f - e)/(1.f + e);
  return copysignf(tt, x);
}
__device__ __forceinline__ float bf2f(u16 u) {
  return __uint_as_float(((unsigned)u) << 16);
}
__device__ __forceinline__ u16 f2bf(float f) {  // round-to-nearest-even
  unsigned u = __float_as_uint(f);
  return (u16)((u + 0x7fffu + ((u >> 16) & 1u)) >> 16);
}

// ---------------- workspace layout ----------------
// fp32 region (element offsets):
constexpr size_t F_B0P  = 0;                               // 2048
constexpr size_t F_B1P  = F_B0P  + 2048;                   // 2048
constexpr size_t F_WX0E = F_B1P  + 2048;                   // 4*2048
constexpr size_t F_PROJ = F_WX0E + 8192;                   // B*S*128
constexpr size_t F_SCORE= F_PROJ + (size_t)BB*SS*HH;       // B*S
constexpr size_t F_BAR  = F_SCORE+ (size_t)BB*SS;          // 64 (barrier cnt/gen)
constexpr size_t F_END  = F_BAR  + 64;
// u16 (bf16) region, starts at byte F_END*4 (16B aligned):
constexpr size_t U_WB0  = 0;                               // 128*16*64*8
constexpr size_t U_WB1  = U_WB0 + (size_t)128*16*64*8;     // 128*32*64*8
constexpr size_t U_H1   = U_WB1 + (size_t)128*32*64*8;     // B*S*512
constexpr size_t U_H2   = U_H1  + (size_t)BB*SS*512;       // B*S*512
constexpr size_t U_ZB   = U_H2  + (size_t)BB*SS*512;       // B*512 zeros
constexpr size_t U_END  = U_ZB  + (size_t)BB*512;
constexpr size_t NEED_BYTES = F_END*4 + U_END*2;

// ---------------- weight expansion into bf16 fragment-major ----------------
// WB[nt][ks][lane][e]: element W[k = ks*32 + (lane>>4)*8 + e][n' = nt*16 + (lane&15)]
__global__ __launch_bounds__(256)
void k_expand(const float* __restrict__ Wh0, const float* __restrict__ Wx1,
              const float* __restrict__ Wh1, const float* __restrict__ Wx0,
              const float* __restrict__ b0,  const float* __restrict__ b1,
              u16* __restrict__ WB0, u16* __restrict__ WB1,
              float* __restrict__ wx0e, float* __restrict__ b0p,
              float* __restrict__ b1p)
{
  const int idx = blockIdx.x*256 + threadIdx.x;   // 0 .. 2M-1 exactly
  { // WB1 (layer 1, K=1024: rows 0..511 = Wx1 on h1_t, 512..1023 = Wh1)
    const int e  = idx & 7;
    const int ln = (idx >> 3) & 63;
    const int ks = (idx >> 9) & 31;
    const int nt = idx >> 14;
    const int k  = ks*32 + (ln >> 4)*8 + e;
    const int np = nt*16 + (ln & 15);
    const int g  = (np >> 2) & 3, co = np & 3;
    const int o  = g*HH + nt;
    const int ci = k & 3;
    const int wi = c_widx[ci*4+co];
    const float sg = c_sgn[ci*4+co];
    const float wv = (k < 512)
      ? Wx1[((size_t)wi*HH + (k >> 2))*512 + o]
      : Wh1[((size_t)wi*HH + ((k - 512) >> 2))*512 + o];
    WB1[idx] = f2bf(sg*wv);
  }
  if (idx < 128*16*64*8) { // WB0 (layer 0 recurrent, K=512)
    const int e  = idx & 7;
    const int ln = (idx >> 3) & 63;
    const int ks = (idx >> 9) & 15;
    const int nt = idx >> 13;
    const int k  = ks*32 + (ln >> 4)*8 + e;
    const int np = nt*16 + (ln & 15);
    const int g  = (np >> 2) & 3, co = np & 3;
    const int o  = g*HH + nt;
    const int ci = k & 3;
    const int wi = c_widx[ci*4+co];
    const float sg = c_sgn[ci*4+co];
    WB0[idx] = f2bf(sg*Wh0[((size_t)wi*HH + (k >> 2))*512 + o]);
  }
  if (idx < 8192) { // wx0e[ci][n'] fp32 (layer-0 input proj, in=1)
    const int ci = idx >> 11, np = idx & 2047;
    const int m = np >> 4, g = (np >> 2) & 3, co = np & 3;
    const int o = g*HH + m;
    wx0e[idx] = c_sgn[ci*4+co]*Wx0[(size_t)c_widx[ci*4+co]*512 + o];
  }
  if (idx < 2048) { // permuted biases fp32
    const int np = idx;
    const int m = np >> 4, g = (np >> 2) & 3, co = np & 3;
    const int o = g*HH + m;
    b0p[idx] = b0[(size_t)o*4 + co];
    b1p[idx] = b1[(size_t)o*4 + co];
  }
}

__global__ __launch_bounds__(256)
void k_init(u16* __restrict__ zb, unsigned* __restrict__ bar)
{
  const int i = blockIdx.x*256 + threadIdx.x;   // 8192 threads
  ((uint4*)zb)[i] = make_uint4(0u,0u,0u,0u);
  if (i < 2) bar[i] = 0u;
}

// ---------------- grid barrier (sense-reversing, agent scope) ----------------
__device__ __forceinline__ void gbar(unsigned* cnt, unsigned* gen)
{
  __syncthreads();
  if (threadIdx.x == 0) {
    __threadfence();
    const unsigned g = __hip_atomic_load(gen, __ATOMIC_ACQUIRE, __HIP_MEMORY_SCOPE_AGENT);
    const unsigned a = __hip_atomic_fetch_add(cnt, 1u, __ATOMIC_ACQ_REL, __HIP_MEMORY_SCOPE_AGENT);
    if (a == NBLK - 1u) {
      __hip_atomic_store(cnt, 0u, __ATOMIC_RELAXED, __HIP_MEMORY_SCOPE_AGENT);
      __hip_atomic_store(gen, g + 1u, __ATOMIC_RELEASE, __HIP_MEMORY_SCOPE_AGENT);
    } else {
      while (__hip_atomic_load(gen, __ATOMIC_ACQUIRE, __HIP_MEMORY_SCOPE_AGENT) == g)
        __builtin_amdgcn_s_sleep(2);
    }
  }
  __syncthreads();
}

// ---------------- persistent fused 2-layer LSTM ----------------
// 256 blocks x 512 threads (8 waves). Waves 0-3: layer0 step t=n.
// Waves 4-7: layer1 step t=n-1 (pipelined). 512 grid barriers total.
// Weights in registers (wf[16]/wf[32]); cell state c in 1 reg/lane.
__global__ __launch_bounds__(512, 2)
void k_lstm(const u16* __restrict__ WB0, const u16* __restrict__ WB1,
            const float* __restrict__ b0p, const float* __restrict__ b1p,
            const float* __restrict__ wx0e, const float* __restrict__ x,
            u16* __restrict__ h1, u16* __restrict__ h2,
            const u16* __restrict__ zb, unsigned* __restrict__ bar)
{
  __shared__ float gs[8][16][17];
  unsigned* cnt = bar;
  unsigned* gen = bar + 16;
  const int tid = threadIdx.x;
  const int w   = tid >> 6;          // wave 0..7
  const int l   = tid & 63;
  const bool isL0 = (w < 4);
  const int wl  = isL0 ? w : (w - 4);
  const int gwv = blockIdx.x*4 + wl; // 0..1023 task id
  const int nt  = gwv & 127;         // h index
  const int r0  = (gwv >> 7)*16;     // batch row base
  const int lrow= l & 15;
  const int lg  = l >> 4;
  const int row = l >> 2, co = l & 3;

  // weights into registers (L0: 16 frags, L1: 32 frags)
  s16x8 wf[32];
  if (isL0) {
    const u16* wb = WB0 + ((size_t)nt*16*64 + l)*8;
    #pragma unroll
    for (int ks = 0; ks < 16; ++ks) wf[ks] = *(const s16x8*)(wb + (size_t)ks*512);
  } else {
    const u16* wb = WB1 + ((size_t)nt*32*64 + l)*8;
    #pragma unroll
    for (int ks = 0; ks < 32; ++ks) wf[ks] = *(const s16x8*)(wb + (size_t)ks*512);
  }
  const float bv = isL0 ? b0p[nt*16 + lrow] : b1p[nt*16 + lrow];
  float xw0=0.f, xw1=0.f, xw2=0.f, xw3=0.f;
  if (isL0) {
    xw0 = wx0e[0*NG + nt*16 + lrow]; xw1 = wx0e[1*NG + nt*16 + lrow];
    xw2 = wx0e[2*NG + nt*16 + lrow]; xw3 = wx0e[3*NG + nt*16 + lrow];
  }
  float creg = 0.f;

  for (int n = 0; n <= SS; ++n) {
    const bool act = isL0 ? (n < SS) : (n >= 1);
    const int t = isL0 ? n : (n - 1);
    if (act) {
      f32x4 acc = {0.f, 0.f, 0.f, 0.f};
      if (isL0) {
        const u16* ap = (t == 0)
          ? (zb + (size_t)(r0 + lrow)*512 + lg*8)
          : (h1 + ((size_t)(r0 + lrow)*SS + (t - 1))*512 + lg*8);
        #pragma unroll
        for (int ks = 0; ks < 16; ++ks) {
          s16x8 a = *(const s16x8*)(ap + (size_t)ks*32);
          acc = __builtin_amdgcn_mfma_f32_16x16x32_bf16(a, wf[ks], acc, 0, 0, 0);
        }
        #pragma unroll
        for (int r = 0; r < 4; ++r) {
          const int brow = r0 + lg*4 + r;
          const float4 xv = *(const float4*)&x[((size_t)brow*SS + t)*4];
          gs[w][lg*4 + r][lrow] = acc[r] + bv
            + xv.x*xw0 + xv.y*xw1 + xv.z*xw2 + xv.w*xw3;
        }
      } else {
        const u16* ap1 = h1 + ((size_t)(r0 + lrow)*SS + t)*512 + lg*8;
        const u16* ap2 = (t == 0)
          ? (zb + (size_t)(r0 + lrow)*512 + lg*8)
          : (h2 + ((size_t)(r0 + lrow)*SS + (t - 1))*512 + lg*8);
        #pragma unroll
        for (int ks = 0; ks < 16; ++ks) {
          s16x8 a = *(const s16x8*)(ap1 + (size_t)ks*32);
          acc = __builtin_amdgcn_mfma_f32_16x16x32_bf16(a, wf[ks], acc, 0, 0, 0);
        }
        #pragma unroll
        for (int ks = 0; ks < 16; ++ks) {
          s16x8 a = *(const s16x8*)(ap2 + (size_t)ks*32);
          acc = __builtin_amdgcn_mfma_f32_16x16x32_bf16(a, wf[16 + ks], acc, 0, 0, 0);
        }
        #pragma unroll
        for (int r = 0; r < 4; ++r)
          gs[w][lg*4 + r][lrow] = acc[r] + bv;
      }
    }
    __syncthreads();
    if (act) {
      const float i_g = fsig (gs[w][row][0*4 + co]);
      const float f_g = fsig (gs[w][row][1*4 + co]);
      const float g_g = ftanh(gs[w][row][2*4 + co]);
      const float o_g = fsig (gs[w][row][3*4 + co]);
      const float cn = f_g*creg + i_g*g_g;
      creg = cn;
      const float hn = o_g*ftanh(cn);
      u16* dst = isL0 ? h1 : h2;
      dst[((size_t)(r0 + row)*SS + t)*512 + nt*4 + co] = f2bf(hn);
    }
    if (n < SS) gbar(cnt, gen);
  }
}

// ---------------- head: projected = h2flat @ Wp + bp ----------------
__global__ __launch_bounds__(256)
void k_proj(const u16* __restrict__ h2, const float* __restrict__ Wp,
            const float* __restrict__ bp, float* __restrict__ proj)
{
  __shared__ float hsh[8][512];
  const int tid = threadIdx.x;
  const int j   = tid & 127;
  const int rh  = tid >> 7;
  const size_t bs0 = (size_t)blockIdx.x * 8;
  for (int f = tid*8; f < 8*512; f += 2048) {
    const int lr = f >> 9, lc = f & 511;
    u16x8 rv = *(const u16x8*)&h2[(bs0 + lr)*512 + lc];
    float4 a, b;
    a.x=bf2f(rv[0]); a.y=bf2f(rv[1]); a.z=bf2f(rv[2]); a.w=bf2f(rv[3]);
    b.x=bf2f(rv[4]); b.y=bf2f(rv[5]); b.z=bf2f(rv[6]); b.w=bf2f(rv[7]);
    *(float4*)&hsh[lr][lc]   = a;
    *(float4*)&hsh[lr][lc+4] = b;
  }
  __syncthreads();
  const float bv = bp[j];
  float a0=bv, a1=bv, a2=bv, a3=bv;
  #pragma unroll 2
  for (int kk = 0; kk < 512; kk += 4) {
    const float w0 = Wp[(size_t)(kk+0)*HH + j];
    const float w1 = Wp[(size_t)(kk+1)*HH + j];
    const float w2 = Wp[(size_t)(kk+2)*HH + j];
    const float w3 = Wp[(size_t)(kk+3)*HH + j];
    const float4 h0 = *(const float4*)&hsh[rh*4+0][kk];
    const float4 h1 = *(const float4*)&hsh[rh*4+1][kk];
    const float4 h2v= *(const float4*)&hsh[rh*4+2][kk];
    const float4 h3 = *(const float4*)&hsh[rh*4+3][kk];
    a0 += h0.x*w0  + h0.y*w1  + h0.z*w2  + h0.w*w3;
    a1 += h1.x*w0  + h1.y*w1  + h1.z*w2  + h1.w*w3;
    a2 += h2v.x*w0 + h2v.y*w1 + h2v.z*w2 + h2v.w*w3;
    a3 += h3.x*w0  + h3.y*w1  + h3.z*w2  + h3.w*w3;
  }
  proj[(bs0 + rh*4+0)*HH + j] = a0;
  proj[(bs0 + rh*4+1)*HH + j] = a1;
  proj[(bs0 + rh*4+2)*HH + j] = a2;
  proj[(bs0 + rh*4+3)*HH + j] = a3;
}

// ---------------- head: scores = tanh(proj @ Wa + ba) @ va ----------------
__global__ __launch_bounds__(256)
void k_scores(const float* __restrict__ proj, const float* __restrict__ Wa,
              const float* __restrict__ ba, const float* __restrict__ va,
              float* __restrict__ scores)
{
  __shared__ float was[64*128];
  __shared__ float ps[32][128];
  __shared__ float red[4];
  const int tid = threadIdx.x;
  const size_t bs0 = (size_t)blockIdx.x * 32;
  for (int f = tid*4; f < 32*128; f += 1024) {
    const int lr = f >> 7, lc = f & 127;
    *(float4*)&ps[lr][lc] = *(const float4*)&proj[(bs0 + lr)*HH + lc];
  }
  const int j  = tid & 127;
  const int rh = tid >> 7;
  float yacc[16];
  const float bav = ba[j];
  #pragma unroll
  for (int rp = 0; rp < 16; ++rp) yacc[rp] = bav;
  for (int half = 0; half < 2; ++half) {
    __syncthreads();
    for (int f = tid*4; f < 64*128; f += 1024)
      *(float4*)&was[f] = *(const float4*)&Wa[(size_t)half*8192 + f];
    __syncthreads();
    for (int rp = 0; rp < 16; ++rp) {
      const int rrow = rp*2 + rh;
      float y = yacc[rp];
      #pragma unroll 8
      for (int i2 = 0; i2 < 64; ++i2)
        y += ps[rrow][half*64 + i2] * was[i2*128 + j];
      yacc[rp] = y;
    }
  }
  const float vav = va[j];
  for (int rp = 0; rp < 16; ++rp) {
    float y = ftanh(yacc[rp]) * vav;
    for (int off = 32; off > 0; off >>= 1) y += __shfl_down(y, off);
    __syncthreads();
    if ((tid & 63) == 0) red[tid >> 6] = y;
    __syncthreads();
    if (tid == 0) scores[bs0 + rp*2 + 0] = red[0] + red[1];
    if (tid == 1) scores[bs0 + rp*2 + 1] = red[2] + red[3];
  }
}

// ---------------- head: softmax + context + output ----------------
__global__ __launch_bounds__(256)
void k_final(const float* __restrict__ proj, const float* __restrict__ scores,
             const float* __restrict__ Wo, const float* __restrict__ bo,
             float* __restrict__ out)
{
  __shared__ float sc[512];
  __shared__ float red[4];
  __shared__ float ctx2[2][128];
  const int tid = threadIdx.x;
  const int b = blockIdx.x;
  *(float2*)&sc[tid*2] = *(const float2*)&scores[(size_t)b*SS + tid*2];
  __syncthreads();
  float m = fmaxf(sc[tid], sc[tid+256]);
  for (int off = 32; off > 0; off >>= 1) m = fmaxf(m, __shfl_down(m, off));
  if ((tid & 63) == 0) red[tid >> 6] = m;
  __syncthreads();
  const float M = fmaxf(fmaxf(red[0], red[1]), fmaxf(red[2], red[3]));
  __syncthreads();
  const float e0 = __expf(sc[tid]     - M);
  const float e1 = __expf(sc[tid+256] - M);
  sc[tid] = e0; sc[tid+256] = e1;
  float s = e0 + e1;
  for (int off = 32; off > 0; off >>= 1) s += __shfl_down(s, off);
  if ((tid & 63) == 0) red[tid >> 6] = s;
  __syncthreads();
  const float rinv = 1.f/(red[0] + red[1] + red[2] + red[3]);
  const int h  = tid & 127;
  const int sh = tid >> 7;
  float cp = 0.f;
  #pragma unroll 4
  for (int ssi = sh*256; ssi < sh*256 + 256; ++ssi)
    cp += sc[ssi]*proj[((size_t)b*SS + ssi)*HH + h];
  ctx2[sh][h] = cp;
  __syncthreads();
  if (tid < 128) {
    const float ctx = (ctx2[0][tid] + ctx2[1][tid])*rinv;
    float v = ctx*Wo[tid];
    for (int off = 32; off > 0; off >>= 1) v += __shfl_down(v, off);
    if ((tid & 63) == 0) red[tid >> 6] = v;
  }
  __syncthreads();
  if (tid == 0) out[b] = red[0] + red[1] + bo[0];
}

// ---------------- host ----------------
extern "C" void kernel_launch(void* const* d_in, const int* in_sizes, int n_in,
                              void* d_out, int out_size, void* d_ws, size_t ws_size,
                              hipStream_t stream)
{
  (void)in_sizes; (void)n_in; (void)out_size;
  const float* x   = (const float*)d_in[0];
  const float* Wx0 = (const float*)d_in[1];
  const float* Wh0 = (const float*)d_in[2];
  const float* b0  = (const float*)d_in[3];
  const float* Wx1 = (const float*)d_in[4];
  const float* Wh1 = (const float*)d_in[5];
  const float* b1  = (const float*)d_in[6];
  const float* Wp  = (const float*)d_in[7];
  const float* bp  = (const float*)d_in[8];
  const float* Wa  = (const float*)d_in[9];
  const float* ba  = (const float*)d_in[10];
  const float* va  = (const float*)d_in[11];
  const float* Wo  = (const float*)d_in[12];
  const float* bo  = (const float*)d_in[13];
  float* ws  = (float*)d_ws;
  u16*   wsu = (u16*)((char*)d_ws + F_END*4);

  if (ws_size < NEED_BYTES) {
    fprintf(stderr, "[qnn] ws too small: have=%zu need=%zu\n", ws_size, NEED_BYTES);
    return;
  }

  k_expand<<<8192, 256, 0, stream>>>(Wh0, Wx1, Wh1, Wx0, b0, b1,
                                     wsu + U_WB0, wsu + U_WB1,
                                     ws + F_WX0E, ws + F_B0P, ws + F_B1P);
  k_init<<<32, 256, 0, stream>>>(wsu + U_ZB, (unsigned*)(ws + F_BAR));

  k_lstm<<<NBLK, 512, 0, stream>>>(wsu + U_WB0, wsu + U_WB1,
                                   ws + F_B0P, ws + F_B1P, ws + F_WX0E, x,
                                   wsu + U_H1, wsu + U_H2, wsu + U_ZB,
                                   (unsigned*)(ws + F_BAR));

  k_proj  <<<BB*SS/8,  256, 0, stream>>>(wsu + U_H2, Wp, bp, ws + F_PROJ);
  k_scores<<<BB*SS/32, 256, 0, stream>>>(ws + F_PROJ, Wa, ba, va, ws + F_SCORE);
  k_final <<<BB,       256, 0, stream>>>(ws + F_PROJ, ws + F_SCORE, Wo, bo,
                                         (float*)d_out);
}

// Round 5
// 14849.870 us; speedup vs baseline: 1.4824x; 1.4824x over previous
//
#include <hip/hip_runtime.h>
#include <cstdio>
#include <cstddef>

#define BB 128
#define SS 512
#define HH 128
#define NG 2048   // 4H*4 components, permuted column layout n' = m*16 + g*4 + co

typedef unsigned short u16;
typedef __attribute__((ext_vector_type(8))) u16   u16x8;
typedef __attribute__((ext_vector_type(8))) short s16x8;
typedef __attribute__((ext_vector_type(4))) float f32x4;

__constant__ int   c_widx[16] = {0,1,2,3, 1,0,3,2, 2,3,0,1, 3,2,1,0};
__constant__ float c_sgn [16] = {1.f,1.f,1.f,1.f, -1.f,1.f,-1.f,1.f,
                                 -1.f,1.f,1.f,-1.f, -1.f,-1.f,1.f,1.f};

__device__ __forceinline__ float fsig(float x) { return 1.f/(1.f + __expf(-x)); }
__device__ __forceinline__ float ftanh(float x) {
  float ax = fabsf(x);
  float e  = __expf(-2.f*ax);
  float tt = (1.f - e)/(1.f + e);
  return copysignf(tt, x);
}
__device__ __forceinline__ float bf2f(u16 u) {
  return __uint_as_float(((unsigned)u) << 16);
}
__device__ __forceinline__ u16 f2bf(float f) {  // round-to-nearest-even
  unsigned u = __float_as_uint(f);
  return (u16)((u + 0x7fffu + ((u >> 16) & 1u)) >> 16);
}

// LLC-coherent (L2-bypassing) 16B load / 2B store: relaxed agent-scope atomics
// emit global_load/store ... sc1 with NO cache-maintenance ops.
__device__ __forceinline__ s16x8 ldh(const u16* p) {
  const unsigned* q = (const unsigned*)p;
  union { unsigned u[4]; s16x8 v; } r;
  r.u[0] = __hip_atomic_load(q+0, __ATOMIC_RELAXED, __HIP_MEMORY_SCOPE_AGENT);
  r.u[1] = __hip_atomic_load(q+1, __ATOMIC_RELAXED, __HIP_MEMORY_SCOPE_AGENT);
  r.u[2] = __hip_atomic_load(q+2, __ATOMIC_RELAXED, __HIP_MEMORY_SCOPE_AGENT);
  r.u[3] = __hip_atomic_load(q+3, __ATOMIC_RELAXED, __HIP_MEMORY_SCOPE_AGENT);
  return r.v;
}
__device__ __forceinline__ void sth(u16* p, u16 v) {
  __hip_atomic_store(p, v, __ATOMIC_RELAXED, __HIP_MEMORY_SCOPE_AGENT);
}

// ---------------- workspace layout ----------------
// fp32 region (element offsets):
constexpr size_t F_B0P  = 0;                               // 2048
constexpr size_t F_B1P  = F_B0P  + 2048;                   // 2048
constexpr size_t F_WX0E = F_B1P  + 2048;                   // 4*2048
constexpr size_t F_PROJ = F_WX0E + 8192;                   // B*S*128
constexpr size_t F_SCORE= F_PROJ + (size_t)BB*SS*HH;       // B*S
constexpr size_t F_BAR  = F_SCORE+ (size_t)BB*SS;          // 8 groups x 64 uints
constexpr size_t F_END  = F_BAR  + 512;
// u16 (bf16) region, starts at byte F_END*4 (16B aligned):
constexpr size_t U_WB0  = 0;                               // 128*16*64*8
constexpr size_t U_WB1  = U_WB0 + (size_t)128*16*64*8;     // 128*32*64*8
constexpr size_t U_H1   = U_WB1 + (size_t)128*32*64*8;     // B*S*512
constexpr size_t U_H2   = U_H1  + (size_t)BB*SS*512;       // B*S*512
constexpr size_t U_END  = U_H2  + (size_t)BB*SS*512;
constexpr size_t NEED_BYTES = F_END*4 + U_END*2;

// ---------------- weight expansion into bf16 fragment-major ----------------
// WB[nt][ks][lane][e]: element W[k = ks*32 + (lane>>4)*8 + e][n' = nt*16 + (lane&15)]
__global__ __launch_bounds__(256)
void k_expand(const float* __restrict__ Wh0, const float* __restrict__ Wx1,
              const float* __restrict__ Wh1, const float* __restrict__ Wx0,
              const float* __restrict__ b0,  const float* __restrict__ b1,
              u16* __restrict__ WB0, u16* __restrict__ WB1,
              float* __restrict__ wx0e, float* __restrict__ b0p,
              float* __restrict__ b1p)
{
  const int idx = blockIdx.x*256 + threadIdx.x;   // 0 .. 2M-1 exactly
  { // WB1 (layer 1, K=1024: rows 0..511 = Wx1 on h1_t, 512..1023 = Wh1)
    const int e  = idx & 7;
    const int ln = (idx >> 3) & 63;
    const int ks = (idx >> 9) & 31;
    const int nt = idx >> 14;
    const int k  = ks*32 + (ln >> 4)*8 + e;
    const int np = nt*16 + (ln & 15);
    const int g  = (np >> 2) & 3, co = np & 3;
    const int o  = g*HH + nt;
    const int ci = k & 3;
    const int wi = c_widx[ci*4+co];
    const float sg = c_sgn[ci*4+co];
    const float wv = (k < 512)
      ? Wx1[((size_t)wi*HH + (k >> 2))*512 + o]
      : Wh1[((size_t)wi*HH + ((k - 512) >> 2))*512 + o];
    WB1[idx] = f2bf(sg*wv);
  }
  if (idx < 128*16*64*8) { // WB0 (layer 0 recurrent, K=512)
    const int e  = idx & 7;
    const int ln = (idx >> 3) & 63;
    const int ks = (idx >> 9) & 15;
    const int nt = idx >> 13;
    const int k  = ks*32 + (ln >> 4)*8 + e;
    const int np = nt*16 + (ln & 15);
    const int g  = (np >> 2) & 3, co = np & 3;
    const int o  = g*HH + nt;
    const int ci = k & 3;
    const int wi = c_widx[ci*4+co];
    const float sg = c_sgn[ci*4+co];
    WB0[idx] = f2bf(sg*Wh0[((size_t)wi*HH + (k >> 2))*512 + o]);
  }
  if (idx < 8192) { // wx0e[ci][n'] fp32 (layer-0 input proj, in=1)
    const int ci = idx >> 11, np = idx & 2047;
    const int m = np >> 4, g = (np >> 2) & 3, co = np & 3;
    const int o = g*HH + m;
    wx0e[idx] = c_sgn[ci*4+co]*Wx0[(size_t)c_widx[ci*4+co]*512 + o];
  }
  if (idx < 2048) { // permuted biases fp32
    const int np = idx;
    const int m = np >> 4, g = (np >> 2) & 3, co = np & 3;
    const int o = g*HH + m;
    b0p[idx] = b0[(size_t)o*4 + co];
    b1p[idx] = b1[(size_t)o*4 + co];
  }
}

__global__ __launch_bounds__(256)
void k_init(unsigned* __restrict__ bar)
{
  const int i = blockIdx.x*256 + threadIdx.x;
  if (i < 512) bar[i] = 0u;
}

// ---------------- per-group barrier (monotonic counter, relaxed) ----------------
// Group = 32 blocks sharing one r0-tile. Data visibility comes from sc1
// (L2-bypass) data ops + the implicit vmcnt(0) drain of __syncthreads before
// the leader's RMW. No fences, no L2 writeback/invalidate anywhere.
__device__ __forceinline__ void gbar(unsigned* cnt, unsigned* gen, unsigned round)
{
  __syncthreads();
  if (threadIdx.x == 0) {
    const unsigned a = __hip_atomic_fetch_add(cnt, 1u, __ATOMIC_RELAXED,
                                              __HIP_MEMORY_SCOPE_AGENT);
    if (a == round*32u + 31u) {
      __hip_atomic_store(gen, round + 1u, __ATOMIC_RELAXED,
                         __HIP_MEMORY_SCOPE_AGENT);
    } else {
      while (__hip_atomic_load(gen, __ATOMIC_RELAXED,
                               __HIP_MEMORY_SCOPE_AGENT) <= round)
        __builtin_amdgcn_s_sleep(1);
    }
  }
  __syncthreads();
}

// ---------------- persistent fused 2-layer LSTM ----------------
// 256 blocks x 512 threads (8 waves). Waves 0-3: layer0 step t=n,
// waves 4-7: layer1 step t=n-1 (pipelined). Barrier only among the 32
// blocks sharing an r0-tile. Weights fully register-resident.
__global__ __launch_bounds__(512, 2)
void k_lstm(const u16* __restrict__ WB0, const u16* __restrict__ WB1,
            const float* __restrict__ b0p, const float* __restrict__ b1p,
            const float* __restrict__ wx0e, const float* __restrict__ x,
            u16* __restrict__ h1, u16* __restrict__ h2,
            unsigned* __restrict__ bar)
{
  __shared__ float gs[8][16][17];
  const int tid = threadIdx.x;
  const int w   = tid >> 6;          // wave 0..7
  const int l   = tid & 63;
  const int grp = blockIdx.x >> 5;   // r0-tile group 0..7
  unsigned* cnt = bar + grp*64;
  unsigned* gen = bar + grp*64 + 32;
  const int lrow = l & 15;
  const int lg   = l >> 4;
  const int row  = l >> 2, co = l & 3;
  float creg = 0.f;

  if (w < 4) {  // ---- layer 0 waves ----
    const int gwv = blockIdx.x*4 + w;
    const int nt  = gwv & 127;
    const int r0  = (gwv >> 7)*16;
    s16x8 wf[16];
    {
      const u16* wb = WB0 + ((size_t)nt*16*64 + l)*8;
      #pragma unroll
      for (int ks = 0; ks < 16; ++ks) wf[ks] = *(const s16x8*)(wb + (size_t)ks*512);
    }
    const float bv  = b0p[nt*16 + lrow];
    const float xw0 = wx0e[0*NG + nt*16 + lrow];
    const float xw1 = wx0e[1*NG + nt*16 + lrow];
    const float xw2 = wx0e[2*NG + nt*16 + lrow];
    const float xw3 = wx0e[3*NG + nt*16 + lrow];
    for (int n = 0; n <= SS; ++n) {
      if (n < SS) {
        const int t = n;
        f32x4 acc = {0.f, 0.f, 0.f, 0.f};
        if (t > 0) {
          const u16* ap = h1 + ((size_t)(r0 + lrow)*SS + (t - 1))*512 + lg*8;
          #pragma unroll
          for (int ks = 0; ks < 16; ++ks)
            acc = __builtin_amdgcn_mfma_f32_16x16x32_bf16(ldh(ap + ks*32), wf[ks], acc, 0, 0, 0);
        }
        #pragma unroll
        for (int r = 0; r < 4; ++r) {
          const int brow = r0 + lg*4 + r;
          const float4 xv = *(const float4*)&x[((size_t)brow*SS + t)*4];
          gs[w][lg*4 + r][lrow] = acc[r] + bv
            + xv.x*xw0 + xv.y*xw1 + xv.z*xw2 + xv.w*xw3;
        }
        // per-wave LDS transpose: no block barrier needed
        const float i_g = fsig (gs[w][row][0*4 + co]);
        const float f_g = fsig (gs[w][row][1*4 + co]);
        const float g_g = ftanh(gs[w][row][2*4 + co]);
        const float o_g = fsig (gs[w][row][3*4 + co]);
        creg = f_g*creg + i_g*g_g;
        const float hn = o_g*ftanh(creg);
        sth(&h1[((size_t)(r0 + row)*SS + t)*512 + nt*4 + co], f2bf(hn));
      }
      if (n < SS) gbar(cnt, gen, (unsigned)n);
    }
  } else {      // ---- layer 1 waves ----
    const int gwv = blockIdx.x*4 + (w - 4);
    const int nt  = gwv & 127;
    const int r0  = (gwv >> 7)*16;
    s16x8 wf[32];
    {
      const u16* wb = WB1 + ((size_t)nt*32*64 + l)*8;
      #pragma unroll
      for (int ks = 0; ks < 32; ++ks) wf[ks] = *(const s16x8*)(wb + (size_t)ks*512);
    }
    const float bv = b1p[nt*16 + lrow];
    for (int n = 0; n <= SS; ++n) {
      if (n >= 1) {
        const int t = n - 1;
        f32x4 acc = {0.f, 0.f, 0.f, 0.f};
        {
          const u16* ap1 = h1 + ((size_t)(r0 + lrow)*SS + t)*512 + lg*8;
          #pragma unroll
          for (int ks = 0; ks < 16; ++ks)
            acc = __builtin_amdgcn_mfma_f32_16x16x32_bf16(ldh(ap1 + ks*32), wf[ks], acc, 0, 0, 0);
        }
        if (t > 0) {
          const u16* ap2 = h2 + ((size_t)(r0 + lrow)*SS + (t - 1))*512 + lg*8;
          #pragma unroll
          for (int ks = 0; ks < 16; ++ks)
            acc = __builtin_amdgcn_mfma_f32_16x16x32_bf16(ldh(ap2 + ks*32), wf[16 + ks], acc, 0, 0, 0);
        }
        #pragma unroll
        for (int r = 0; r < 4; ++r)
          gs[w][lg*4 + r][lrow] = acc[r] + bv;
        const float i_g = fsig (gs[w][row][0*4 + co]);
        const float f_g = fsig (gs[w][row][1*4 + co]);
        const float g_g = ftanh(gs[w][row][2*4 + co]);
        const float o_g = fsig (gs[w][row][3*4 + co]);
        creg = f_g*creg + i_g*g_g;
        const float hn = o_g*ftanh(creg);
        sth(&h2[((size_t)(r0 + row)*SS + t)*512 + nt*4 + co], f2bf(hn));
      }
      if (n < SS) gbar(cnt, gen, (unsigned)n);
    }
  }
}

// ---------------- head: projected = h2flat @ Wp + bp ----------------
__global__ __launch_bounds__(256)
void k_proj(const u16* __restrict__ h2, const float* __restrict__ Wp,
            const float* __restrict__ bp, float* __restrict__ proj)
{
  __shared__ float hsh[8][512];
  const int tid = threadIdx.x;
  const int j   = tid & 127;
  const int rh  = tid >> 7;
  const size_t bs0 = (size_t)blockIdx.x * 8;
  for (int f = tid*8; f < 8*512; f += 2048) {
    const int lr = f >> 9, lc = f & 511;
    u16x8 rv = *(const u16x8*)&h2[(bs0 + lr)*512 + lc];
    float4 a, b;
    a.x=bf2f(rv[0]); a.y=bf2f(rv[1]); a.z=bf2f(rv[2]); a.w=bf2f(rv[3]);
    b.x=bf2f(rv[4]); b.y=bf2f(rv[5]); b.z=bf2f(rv[6]); b.w=bf2f(rv[7]);
    *(float4*)&hsh[lr][lc]   = a;
    *(float4*)&hsh[lr][lc+4] = b;
  }
  __syncthreads();
  const float bv = bp[j];
  float a0=bv, a1=bv, a2=bv, a3=bv;
  #pragma unroll 2
  for (int kk = 0; kk < 512; kk += 4) {
    const float w0 = Wp[(size_t)(kk+0)*HH + j];
    const float w1 = Wp[(size_t)(kk+1)*HH + j];
    const float w2 = Wp[(size_t)(kk+2)*HH + j];
    const float w3 = Wp[(size_t)(kk+3)*HH + j];
    const float4 h0 = *(const float4*)&hsh[rh*4+0][kk];
    const float4 h1 = *(const float4*)&hsh[rh*4+1][kk];
    const float4 h2v= *(const float4*)&hsh[rh*4+2][kk];
    const float4 h3 = *(const float4*)&hsh[rh*4+3][kk];
    a0 += h0.x*w0  + h0.y*w1  + h0.z*w2  + h0.w*w3;
    a1 += h1.x*w0  + h1.y*w1  + h1.z*w2  + h1.w*w3;
    a2 += h2v.x*w0 + h2v.y*w1 + h2v.z*w2 + h2v.w*w3;
    a3 += h3.x*w0  + h3.y*w1  + h3.z*w2  + h3.w*w3;
  }
  proj[(bs0 + rh*4+0)*HH + j] = a0;
  proj[(bs0 + rh*4+1)*HH + j] = a1;
  proj[(bs0 + rh*4+2)*HH + j] = a2;
  proj[(bs0 + rh*4+3)*HH + j] = a3;
}

// ---------------- head: scores = tanh(proj @ Wa + ba) @ va ----------------
__global__ __launch_bounds__(256)
void k_scores(const float* __restrict__ proj, const float* __restrict__ Wa,
              const float* __restrict__ ba, const float* __restrict__ va,
              float* __restrict__ scores)
{
  __shared__ float was[64*128];
  __shared__ float ps[32][128];
  __shared__ float red[4];
  const int tid = threadIdx.x;
  const size_t bs0 = (size_t)blockIdx.x * 32;
  for (int f = tid*4; f < 32*128; f += 1024) {
    const int lr = f >> 7, lc = f & 127;
    *(float4*)&ps[lr][lc] = *(const float4*)&proj[(bs0 + lr)*HH + lc];
  }
  const int j  = tid & 127;
  const int rh = tid >> 7;
  float yacc[16];
  const float bav = ba[j];
  #pragma unroll
  for (int rp = 0; rp < 16; ++rp) yacc[rp] = bav;
  for (int half = 0; half < 2; ++half) {
    __syncthreads();
    for (int f = tid*4; f < 64*128; f += 1024)
      *(float4*)&was[f] = *(const float4*)&Wa[(size_t)half*8192 + f];
    __syncthreads();
    for (int rp = 0; rp < 16; ++rp) {
      const int rrow = rp*2 + rh;
      float y = yacc[rp];
      #pragma unroll 8
      for (int i2 = 0; i2 < 64; ++i2)
        y += ps[rrow][half*64 + i2] * was[i2*128 + j];
      yacc[rp] = y;
    }
  }
  const float vav = va[j];
  for (int rp = 0; rp < 16; ++rp) {
    float y = ftanh(yacc[rp]) * vav;
    for (int off = 32; off > 0; off >>= 1) y += __shfl_down(y, off);
    __syncthreads();
    if ((tid & 63) == 0) red[tid >> 6] = y;
    __syncthreads();
    if (tid == 0) scores[bs0 + rp*2 + 0] = red[0] + red[1];
    if (tid == 1) scores[bs0 + rp*2 + 1] = red[2] + red[3];
  }
}

// ---------------- head: softmax + context + output ----------------
__global__ __launch_bounds__(256)
void k_final(const float* __restrict__ proj, const float* __restrict__ scores,
             const float* __restrict__ Wo, const float* __restrict__ bo,
             float* __restrict__ out)
{
  __shared__ float sc[512];
  __shared__ float red[4];
  __shared__ float ctx2[2][128];
  const int tid = threadIdx.x;
  const int b = blockIdx.x;
  *(float2*)&sc[tid*2] = *(const float2*)&scores[(size_t)b*SS + tid*2];
  __syncthreads();
  float m = fmaxf(sc[tid], sc[tid+256]);
  for (int off = 32; off > 0; off >>= 1) m = fmaxf(m, __shfl_down(m, off));
  if ((tid & 63) == 0) red[tid >> 6] = m;
  __syncthreads();
  const float M = fmaxf(fmaxf(red[0], red[1]), fmaxf(red[2], red[3]));
  __syncthreads();
  const float e0 = __expf(sc[tid]     - M);
  const float e1 = __expf(sc[tid+256] - M);
  sc[tid] = e0; sc[tid+256] = e1;
  float s = e0 + e1;
  for (int off = 32; off > 0; off >>= 1) s += __shfl_down(s, off);
  if ((tid & 63) == 0) red[tid >> 6] = s;
  __syncthreads();
  const float rinv = 1.f/(red[0] + red[1] + red[2] + red[3]);
  const int h  = tid & 127;
  const int sh = tid >> 7;
  float cp = 0.f;
  #pragma unroll 4
  for (int ssi = sh*256; ssi < sh*256 + 256; ++ssi)
    cp += sc[ssi]*proj[((size_t)b*SS + ssi)*HH + h];
  ctx2[sh][h] = cp;
  __syncthreads();
  if (tid < 128) {
    const float ctx = (ctx2[0][tid] + ctx2[1][tid])*rinv;
    float v = ctx*Wo[tid];
    for (int off = 32; off > 0; off >>= 1) v += __shfl_down(v, off);
    if ((tid & 63) == 0) red[tid >> 6] = v;
  }
  __syncthreads();
  if (tid == 0) out[b] = red[0] + red[1] + bo[0];
}

// ---------------- host ----------------
extern "C" void kernel_launch(void* const* d_in, const int* in_sizes, int n_in,
                              void* d_out, int out_size, void* d_ws, size_t ws_size,
                              hipStream_t stream)
{
  (void)in_sizes; (void)n_in; (void)out_size;
  const float* x   = (const float*)d_in[0];
  const float* Wx0 = (const float*)d_in[1];
  const float* Wh0 = (const float*)d_in[2];
  const float* b0  = (const float*)d_in[3];
  const float* Wx1 = (const float*)d_in[4];
  const float* Wh1 = (const float*)d_in[5];
  const float* b1  = (const float*)d_in[6];
  const float* Wp  = (const float*)d_in[7];
  const float* bp  = (const float*)d_in[8];
  const float* Wa  = (const float*)d_in[9];
  const float* ba  = (const float*)d_in[10];
  const float* va  = (const float*)d_in[11];
  const float* Wo  = (const float*)d_in[12];
  const float* bo  = (const float*)d_in[13];
  float* ws  = (float*)d_ws;
  u16*   wsu = (u16*)((char*)d_ws + F_END*4);

  if (ws_size < NEED_BYTES) {
    fprintf(stderr, "[qnn] ws too small: have=%zu need=%zu\n", ws_size, NEED_BYTES);
    return;
  }

  k_expand<<<8192, 256, 0, stream>>>(Wh0, Wx1, Wh1, Wx0, b0, b1,
                                     wsu + U_WB0, wsu + U_WB1,
                                     ws + F_WX0E, ws + F_B0P, ws + F_B1P);
  k_init<<<2, 256, 0, stream>>>((unsigned*)(ws + F_BAR));

  k_lstm<<<256, 512, 0, stream>>>(wsu + U_WB0, wsu + U_WB1,
                                  ws + F_B0P, ws + F_B1P, ws + F_WX0E, x,
                                  wsu + U_H1, wsu + U_H2,
                                  (unsigned*)(ws + F_BAR));

  k_proj  <<<BB*SS/8,  256, 0, stream>>>(wsu + U_H2, Wp, bp, ws + F_PROJ);
  k_scores<<<BB*SS/32, 256, 0, stream>>>(ws + F_PROJ, Wa, ba, va, ws + F_SCORE);
  k_final <<<BB,       256, 0, stream>>>(ws + F_PROJ, ws + F_SCORE, Wo, bo,
                                         (float*)d_out);
}

// Round 6
// 4944.590 us; speedup vs baseline: 4.4521x; 3.0033x over previous
//
#include <hip/hip_runtime.h>
#include <cstdio>
#include <cstddef>

#define BB 128
#define SS 512
#define HH 128
#define NG 2048   // 4H*4 components, permuted column layout n' = m*16 + g*4 + co

typedef unsigned short u16;
typedef __attribute__((ext_vector_type(8))) u16   u16x8;
typedef __attribute__((ext_vector_type(8))) short s16x8;
typedef __attribute__((ext_vector_type(4))) float f32x4;

__constant__ int   c_widx[16] = {0,1,2,3, 1,0,3,2, 2,3,0,1, 3,2,1,0};
__constant__ float c_sgn [16] = {1.f,1.f,1.f,1.f, -1.f,1.f,-1.f,1.f,
                                 -1.f,1.f,1.f,-1.f, -1.f,-1.f,1.f,1.f};

__device__ __forceinline__ float fsig(float x) { return 1.f/(1.f + __expf(-x)); }
__device__ __forceinline__ float ftanh(float x) {
  float ax = fabsf(x);
  float e  = __expf(-2.f*ax);
  float tt = (1.f - e)/(1.f + e);
  return copysignf(tt, x);
}
__device__ __forceinline__ float bf2f(u16 u) {
  return __uint_as_float(((unsigned)u) << 16);
}
__device__ __forceinline__ u16 f2bf(float f) {  // round-to-nearest-even
  unsigned u = __float_as_uint(f);
  return (u16)((u + 0x7fffu + ((u >> 16) & 1u)) >> 16);
}

// Write-through store (LLC-visible, bypasses the non-coherent per-XCD L2).
// Reads of h use PLAIN cached loads: every h address is fresh-per-t inside the
// kernel (one 128B line holds one (b,t) only), so reader L2s can't be stale;
// their miss pulls the sc1-written truth from LLC.
__device__ __forceinline__ void sth(u16* p, u16 v) {
  __hip_atomic_store(p, v, __ATOMIC_RELAXED, __HIP_MEMORY_SCOPE_AGENT);
}

// ---------------- workspace layout ----------------
// fp32 region (element offsets):
constexpr size_t F_B0P  = 0;                               // 2048
constexpr size_t F_B1P  = F_B0P  + 2048;                   // 2048
constexpr size_t F_WX0E = F_B1P  + 2048;                   // 4*2048
constexpr size_t F_PROJ = F_WX0E + 8192;                   // B*S*128
constexpr size_t F_SCORE= F_PROJ + (size_t)BB*SS*HH;       // B*S
constexpr size_t F_BAR  = F_SCORE+ (size_t)BB*SS;          // 8 groups x 64 uints
constexpr size_t F_END  = F_BAR  + 512;
// u16 (bf16) region, starts at byte F_END*4 (16B aligned):
constexpr size_t U_WB0  = 0;                               // 128*16*64*8
constexpr size_t U_WB1  = U_WB0 + (size_t)128*16*64*8;     // 128*32*64*8
constexpr size_t U_H1   = U_WB1 + (size_t)128*32*64*8;     // B*S*512
constexpr size_t U_H2   = U_H1  + (size_t)BB*SS*512;       // B*S*512
constexpr size_t U_END  = U_H2  + (size_t)BB*SS*512;
constexpr size_t NEED_BYTES = F_END*4 + U_END*2;

// ---------------- weight expansion into bf16 fragment-major ----------------
// WB[nt][ks][lane][e]: element W[k = ks*32 + (lane>>4)*8 + e][n' = nt*16 + (lane&15)]
__global__ __launch_bounds__(256)
void k_expand(const float* __restrict__ Wh0, const float* __restrict__ Wx1,
              const float* __restrict__ Wh1, const float* __restrict__ Wx0,
              const float* __restrict__ b0,  const float* __restrict__ b1,
              u16* __restrict__ WB0, u16* __restrict__ WB1,
              float* __restrict__ wx0e, float* __restrict__ b0p,
              float* __restrict__ b1p)
{
  const int idx = blockIdx.x*256 + threadIdx.x;   // 0 .. 2M-1 exactly
  { // WB1 (layer 1, K=1024: rows 0..511 = Wx1 on h1_t, 512..1023 = Wh1)
    const int e  = idx & 7;
    const int ln = (idx >> 3) & 63;
    const int ks = (idx >> 9) & 31;
    const int nt = idx >> 14;
    const int k  = ks*32 + (ln >> 4)*8 + e;
    const int np = nt*16 + (ln & 15);
    const int g  = (np >> 2) & 3, co = np & 3;
    const int o  = g*HH + nt;
    const int ci = k & 3;
    const int wi = c_widx[ci*4+co];
    const float sg = c_sgn[ci*4+co];
    const float wv = (k < 512)
      ? Wx1[((size_t)wi*HH + (k >> 2))*512 + o]
      : Wh1[((size_t)wi*HH + ((k - 512) >> 2))*512 + o];
    WB1[idx] = f2bf(sg*wv);
  }
  if (idx < 128*16*64*8) { // WB0 (layer 0 recurrent, K=512)
    const int e  = idx & 7;
    const int ln = (idx >> 3) & 63;
    const int ks = (idx >> 9) & 15;
    const int nt = idx >> 13;
    const int k  = ks*32 + (ln >> 4)*8 + e;
    const int np = nt*16 + (ln & 15);
    const int g  = (np >> 2) & 3, co = np & 3;
    const int o  = g*HH + nt;
    const int ci = k & 3;
    const int wi = c_widx[ci*4+co];
    const float sg = c_sgn[ci*4+co];
    WB0[idx] = f2bf(sg*Wh0[((size_t)wi*HH + (k >> 2))*512 + o]);
  }
  if (idx < 8192) { // wx0e[ci][n'] fp32 (layer-0 input proj, in=1)
    const int ci = idx >> 11, np = idx & 2047;
    const int m = np >> 4, g = (np >> 2) & 3, co = np & 3;
    const int o = g*HH + m;
    wx0e[idx] = c_sgn[ci*4+co]*Wx0[(size_t)c_widx[ci*4+co]*512 + o];
  }
  if (idx < 2048) { // permuted biases fp32
    const int np = idx;
    const int m = np >> 4, g = (np >> 2) & 3, co = np & 3;
    const int o = g*HH + m;
    b0p[idx] = b0[(size_t)o*4 + co];
    b1p[idx] = b1[(size_t)o*4 + co];
  }
}

__global__ __launch_bounds__(256)
void k_init(unsigned* __restrict__ bar)
{
  const int i = blockIdx.x*256 + threadIdx.x;
  if (i < 512) bar[i] = 0u;
}

// ---------------- per-group barrier (monotonic counter, relaxed) ----------------
// Group = 32 blocks sharing one r0-tile. No acquire/release anywhere: an
// agent-scope acquire would emit L2 invalidates and evict the XCD-resident
// weight slice every round. Visibility comes from sc1 data stores (drained by
// the pre-RMW __syncthreads) + fresh-address cached reads. asm clobber stops
// the compiler hoisting reads above the spin.
__device__ __forceinline__ void gbar(unsigned* cnt, unsigned* gen, unsigned round)
{
  __syncthreads();
  if (threadIdx.x == 0) {
    const unsigned a = __hip_atomic_fetch_add(cnt, 1u, __ATOMIC_RELAXED,
                                              __HIP_MEMORY_SCOPE_AGENT);
    if (a == round*32u + 31u) {
      __hip_atomic_store(gen, round + 1u, __ATOMIC_RELAXED,
                         __HIP_MEMORY_SCOPE_AGENT);
    } else {
      while (__hip_atomic_load(gen, __ATOMIC_RELAXED,
                               __HIP_MEMORY_SCOPE_AGENT) <= round)
        __builtin_amdgcn_s_sleep(1);
    }
  }
  __syncthreads();
  asm volatile("" ::: "memory");
}

// ---------------- persistent fused 2-layer LSTM ----------------
// 256 blocks x 512 threads (8 waves). XCD-aware mapping: xcd=bid&7 owns
// nt in [xcd*16, xcd*16+16) -> per-XCD weight slice = 768 KB (L2-resident).
// grp=(bid>>5 ordering replaced): grp=(bid>>3)>>2 indexes the r0-tile; the
// 32 blocks of a group span all 8 XCDs. Waves 0-3: layer0 step t=n,
// waves 4-7: layer1 step t=n-1 (pipelined). Weights preloaded to wf[].
__global__ __launch_bounds__(512, 1)
void k_lstm(const u16* __restrict__ WB0, const u16* __restrict__ WB1,
            const float* __restrict__ b0p, const float* __restrict__ b1p,
            const float* __restrict__ wx0e, const float* __restrict__ x,
            u16* __restrict__ h1, u16* __restrict__ h2,
            unsigned* __restrict__ bar)
{
  __shared__ float gs[8][16][17];
  const int tid = threadIdx.x;
  const int w   = tid >> 6;          // wave 0..7
  const int l   = tid & 63;
  const int bid = blockIdx.x;
  const int xcd = bid & 7;
  const int j   = bid >> 3;          // 0..31
  const int grp = j >> 2;            // r0-tile group 0..7
  const int jj  = j & 3;             // nt sub-slice 0..3
  const int r0  = grp*16;
  unsigned* cnt = bar + grp*64;
  unsigned* gen = bar + grp*64 + 32;
  const int lrow = l & 15;
  const int lg   = l >> 4;
  const int row  = l >> 2, co = l & 3;
  float creg = 0.f;

  if (w < 4) {  // ---- layer 0 waves ----
    const int nt = xcd*16 + jj*4 + w;
    s16x8 wf[16];
    {
      const u16* wb = WB0 + ((size_t)nt*16*64 + l)*8;
      #pragma unroll
      for (int ks = 0; ks < 16; ++ks) wf[ks] = *(const s16x8*)(wb + (size_t)ks*512);
    }
    const float bv  = b0p[nt*16 + lrow];
    const float xw0 = wx0e[0*NG + nt*16 + lrow];
    const float xw1 = wx0e[1*NG + nt*16 + lrow];
    const float xw2 = wx0e[2*NG + nt*16 + lrow];
    const float xw3 = wx0e[3*NG + nt*16 + lrow];
    for (int n = 0; n <= SS; ++n) {
      if (n < SS) {
        const int t = n;
        f32x4 acc = {0.f, 0.f, 0.f, 0.f};
        if (t > 0) {
          const u16* ap = h1 + ((size_t)(r0 + lrow)*SS + (t - 1))*512 + lg*8;
          #pragma unroll
          for (int ks = 0; ks < 16; ++ks) {
            s16x8 a = *(const s16x8*)(ap + (size_t)ks*32);
            acc = __builtin_amdgcn_mfma_f32_16x16x32_bf16(a, wf[ks], acc, 0, 0, 0);
          }
        }
        #pragma unroll
        for (int r = 0; r < 4; ++r) {
          const int brow = r0 + lg*4 + r;
          const float4 xv = *(const float4*)&x[((size_t)brow*SS + t)*4];
          gs[w][lg*4 + r][lrow] = acc[r] + bv
            + xv.x*xw0 + xv.y*xw1 + xv.z*xw2 + xv.w*xw3;
        }
        // per-wave LDS transpose: no block barrier needed
        const float i_g = fsig (gs[w][row][0*4 + co]);
        const float f_g = fsig (gs[w][row][1*4 + co]);
        const float g_g = ftanh(gs[w][row][2*4 + co]);
        const float o_g = fsig (gs[w][row][3*4 + co]);
        creg = f_g*creg + i_g*g_g;
        const float hn = o_g*ftanh(creg);
        sth(&h1[((size_t)(r0 + row)*SS + t)*512 + nt*4 + co], f2bf(hn));
      }
      if (n < SS) gbar(cnt, gen, (unsigned)n);
    }
  } else {      // ---- layer 1 waves ----
    const int nt = xcd*16 + jj*4 + (w - 4);
    s16x8 wf[32];
    {
      const u16* wb = WB1 + ((size_t)nt*32*64 + l)*8;
      #pragma unroll
      for (int ks = 0; ks < 32; ++ks) wf[ks] = *(const s16x8*)(wb + (size_t)ks*512);
    }
    const float bv = b1p[nt*16 + lrow];
    for (int n = 0; n <= SS; ++n) {
      if (n >= 1) {
        const int t = n - 1;
        f32x4 acc = {0.f, 0.f, 0.f, 0.f};
        {
          const u16* ap1 = h1 + ((size_t)(r0 + lrow)*SS + t)*512 + lg*8;
          #pragma unroll
          for (int ks = 0; ks < 16; ++ks) {
            s16x8 a = *(const s16x8*)(ap1 + (size_t)ks*32);
            acc = __builtin_amdgcn_mfma_f32_16x16x32_bf16(a, wf[ks], acc, 0, 0, 0);
          }
        }
        if (t > 0) {
          const u16* ap2 = h2 + ((size_t)(r0 + lrow)*SS + (t - 1))*512 + lg*8;
          #pragma unroll
          for (int ks = 0; ks < 16; ++ks) {
            s16x8 a = *(const s16x8*)(ap2 + (size_t)ks*32);
            acc = __builtin_amdgcn_mfma_f32_16x16x32_bf16(a, wf[16 + ks], acc, 0, 0, 0);
          }
        }
        #pragma unroll
        for (int r = 0; r < 4; ++r)
          gs[w][lg*4 + r][lrow] = acc[r] + bv;
        const float i_g = fsig (gs[w][row][0*4 + co]);
        const float f_g = fsig (gs[w][row][1*4 + co]);
        const float g_g = ftanh(gs[w][row][2*4 + co]);
        const float o_g = fsig (gs[w][row][3*4 + co]);
        creg = f_g*creg + i_g*g_g;
        const float hn = o_g*ftanh(creg);
        sth(&h2[((size_t)(r0 + row)*SS + t)*512 + nt*4 + co], f2bf(hn));
      }
      if (n < SS) gbar(cnt, gen, (unsigned)n);
    }
  }
}

// ---------------- head: projected = h2flat @ Wp + bp ----------------
__global__ __launch_bounds__(256)
void k_proj(const u16* __restrict__ h2, const float* __restrict__ Wp,
            const float* __restrict__ bp, float* __restrict__ proj)
{
  __shared__ float hsh[8][512];
  const int tid = threadIdx.x;
  const int j   = tid & 127;
  const int rh  = tid >> 7;
  const size_t bs0 = (size_t)blockIdx.x * 8;
  for (int f = tid*8; f < 8*512; f += 2048) {
    const int lr = f >> 9, lc = f & 511;
    u16x8 rv = *(const u16x8*)&h2[(bs0 + lr)*512 + lc];
    float4 a, b;
    a.x=bf2f(rv[0]); a.y=bf2f(rv[1]); a.z=bf2f(rv[2]); a.w=bf2f(rv[3]);
    b.x=bf2f(rv[4]); b.y=bf2f(rv[5]); b.z=bf2f(rv[6]); b.w=bf2f(rv[7]);
    *(float4*)&hsh[lr][lc]   = a;
    *(float4*)&hsh[lr][lc+4] = b;
  }
  __syncthreads();
  const float bv = bp[j];
  float a0=bv, a1=bv, a2=bv, a3=bv;
  #pragma unroll 2
  for (int kk = 0; kk < 512; kk += 4) {
    const float w0 = Wp[(size_t)(kk+0)*HH + j];
    const float w1 = Wp[(size_t)(kk+1)*HH + j];
    const float w2 = Wp[(size_t)(kk+2)*HH + j];
    const float w3 = Wp[(size_t)(kk+3)*HH + j];
    const float4 h0 = *(const float4*)&hsh[rh*4+0][kk];
    const float4 h1 = *(const float4*)&hsh[rh*4+1][kk];
    const float4 h2v= *(const float4*)&hsh[rh*4+2][kk];
    const float4 h3 = *(const float4*)&hsh[rh*4+3][kk];
    a0 += h0.x*w0  + h0.y*w1  + h0.z*w2  + h0.w*w3;
    a1 += h1.x*w0  + h1.y*w1  + h1.z*w2  + h1.w*w3;
    a2 += h2v.x*w0 + h2v.y*w1 + h2v.z*w2 + h2v.w*w3;
    a3 += h3.x*w0  + h3.y*w1  + h3.z*w2  + h3.w*w3;
  }
  proj[(bs0 + rh*4+0)*HH + j] = a0;
  proj[(bs0 + rh*4+1)*HH + j] = a1;
  proj[(bs0 + rh*4+2)*HH + j] = a2;
  proj[(bs0 + rh*4+3)*HH + j] = a3;
}

// ---------------- head: scores = tanh(proj @ Wa + ba) @ va ----------------
__global__ __launch_bounds__(256)
void k_scores(const float* __restrict__ proj, const float* __restrict__ Wa,
              const float* __restrict__ ba, const float* __restrict__ va,
              float* __restrict__ scores)
{
  __shared__ float was[64*128];
  __shared__ float ps[32][128];
  __shared__ float red[4];
  const int tid = threadIdx.x;
  const size_t bs0 = (size_t)blockIdx.x * 32;
  for (int f = tid*4; f < 32*128; f += 1024) {
    const int lr = f >> 7, lc = f & 127;
    *(float4*)&ps[lr][lc] = *(const float4*)&proj[(bs0 + lr)*HH + lc];
  }
  const int j  = tid & 127;
  const int rh = tid >> 7;
  float yacc[16];
  const float bav = ba[j];
  #pragma unroll
  for (int rp = 0; rp < 16; ++rp) yacc[rp] = bav;
  for (int half = 0; half < 2; ++half) {
    __syncthreads();
    for (int f = tid*4; f < 64*128; f += 1024)
      *(float4*)&was[f] = *(const float4*)&Wa[(size_t)half*8192 + f];
    __syncthreads();
    for (int rp = 0; rp < 16; ++rp) {
      const int rrow = rp*2 + rh;
      float y = yacc[rp];
      #pragma unroll 8
      for (int i2 = 0; i2 < 64; ++i2)
        y += ps[rrow][half*64 + i2] * was[i2*128 + j];
      yacc[rp] = y;
    }
  }
  const float vav = va[j];
  for (int rp = 0; rp < 16; ++rp) {
    float y = ftanh(yacc[rp]) * vav;
    for (int off = 32; off > 0; off >>= 1) y += __shfl_down(y, off);
    __syncthreads();
    if ((tid & 63) == 0) red[tid >> 6] = y;
    __syncthreads();
    if (tid == 0) scores[bs0 + rp*2 + 0] = red[0] + red[1];
    if (tid == 1) scores[bs0 + rp*2 + 1] = red[2] + red[3];
  }
}

// ---------------- head: softmax + context + output ----------------
__global__ __launch_bounds__(256)
void k_final(const float* __restrict__ proj, const float* __restrict__ scores,
             const float* __restrict__ Wo, const float* __restrict__ bo,
             float* __restrict__ out)
{
  __shared__ float sc[512];
  __shared__ float red[4];
  __shared__ float ctx2[2][128];
  const int tid = threadIdx.x;
  const int b = blockIdx.x;
  *(float2*)&sc[tid*2] = *(const float2*)&scores[(size_t)b*SS + tid*2];
  __syncthreads();
  float m = fmaxf(sc[tid], sc[tid+256]);
  for (int off = 32; off > 0; off >>= 1) m = fmaxf(m, __shfl_down(m, off));
  if ((tid & 63) == 0) red[tid >> 6] = m;
  __syncthreads();
  const float M = fmaxf(fmaxf(red[0], red[1]), fmaxf(red[2], red[3]));
  __syncthreads();
  const float e0 = __expf(sc[tid]     - M);
  const float e1 = __expf(sc[tid+256] - M);
  sc[tid] = e0; sc[tid+256] = e1;
  float s = e0 + e1;
  for (int off = 32; off > 0; off >>= 1) s += __shfl_down(s, off);
  if ((tid & 63) == 0) red[tid >> 6] = s;
  __syncthreads();
  const float rinv = 1.f/(red[0] + red[1] + red[2] + red[3]);
  const int h  = tid & 127;
  const int sh = tid >> 7;
  float cp = 0.f;
  #pragma unroll 4
  for (int ssi = sh*256; ssi < sh*256 + 256; ++ssi)
    cp += sc[ssi]*proj[((size_t)b*SS + ssi)*HH + h];
  ctx2[sh][h] = cp;
  __syncthreads();
  if (tid < 128) {
    const float ctx = (ctx2[0][tid] + ctx2[1][tid])*rinv;
    float v = ctx*Wo[tid];
    for (int off = 32; off > 0; off >>= 1) v += __shfl_down(v, off);
    if ((tid & 63) == 0) red[tid >> 6] = v;
  }
  __syncthreads();
  if (tid == 0) out[b] = red[0] + red[1] + bo[0];
}

// ---------------- host ----------------
extern "C" void kernel_launch(void* const* d_in, const int* in_sizes, int n_in,
                              void* d_out, int out_size, void* d_ws, size_t ws_size,
                              hipStream_t stream)
{
  (void)in_sizes; (void)n_in; (void)out_size;
  const float* x   = (const float*)d_in[0];
  const float* Wx0 = (const float*)d_in[1];
  const float* Wh0 = (const float*)d_in[2];
  const float* b0  = (const float*)d_in[3];
  const float* Wx1 = (const float*)d_in[4];
  const float* Wh1 = (const float*)d_in[5];
  const float* b1  = (const float*)d_in[6];
  const float* Wp  = (const float*)d_in[7];
  const float* bp  = (const float*)d_in[8];
  const float* Wa  = (const float*)d_in[9];
  const float* ba  = (const float*)d_in[10];
  const float* va  = (const float*)d_in[11];
  const float* Wo  = (const float*)d_in[12];
  const float* bo  = (const float*)d_in[13];
  float* ws  = (float*)d_ws;
  u16*   wsu = (u16*)((char*)d_ws + F_END*4);

  if (ws_size < NEED_BYTES) {
    fprintf(stderr, "[qnn] ws too small: have=%zu need=%zu\n", ws_size, NEED_BYTES);
    return;
  }

  k_expand<<<8192, 256, 0, stream>>>(Wh0, Wx1, Wh1, Wx0, b0, b1,
                                     wsu + U_WB0, wsu + U_WB1,
                                     ws + F_WX0E, ws + F_B0P, ws + F_B1P);
  k_init<<<2, 256, 0, stream>>>((unsigned*)(ws + F_BAR));

  k_lstm<<<256, 512, 0, stream>>>(wsu + U_WB0, wsu + U_WB1,
                                  ws + F_B0P, ws + F_B1P, ws + F_WX0E, x,
                                  wsu + U_H1, wsu + U_H2,
                                  (unsigned*)(ws + F_BAR));

  k_proj  <<<BB*SS/8,  256, 0, stream>>>(wsu + U_H2, Wp, bp, ws + F_PROJ);
  k_scores<<<BB*SS/32, 256, 0, stream>>>(ws + F_PROJ, Wa, ba, va, ws + F_SCORE);
  k_final <<<BB,       256, 0, stream>>>(ws + F_PROJ, ws + F_SCORE, Wo, bo,
                                         (float*)d_out);
}

// Round 7
// 4835.595 us; speedup vs baseline: 4.5525x; 1.0225x over previous
//
#include <hip/hip_runtime.h>
#include <cstdio>
#include <cstddef>

#define BB 128
#define SS 512
#define HH 128
#define NG 2048   // 4H*4 components, permuted column layout n' = m*16 + g*4 + co

typedef unsigned short u16;
typedef __attribute__((ext_vector_type(8))) u16   u16x8;
typedef __attribute__((ext_vector_type(8))) short s16x8;
typedef __attribute__((ext_vector_type(4))) float f32x4;

__constant__ int   c_widx[16] = {0,1,2,3, 1,0,3,2, 2,3,0,1, 3,2,1,0};
__constant__ float c_sgn [16] = {1.f,1.f,1.f,1.f, -1.f,1.f,-1.f,1.f,
                                 -1.f,1.f,1.f,-1.f, -1.f,-1.f,1.f,1.f};

__device__ __forceinline__ float fsig(float x) { return 1.f/(1.f + __expf(-x)); }
__device__ __forceinline__ float ftanh(float x) {
  float ax = fabsf(x);
  float e  = __expf(-2.f*ax);
  float tt = (1.f - e)/(1.f + e);
  return copysignf(tt, x);
}
__device__ __forceinline__ float bf2f(u16 u) {
  return __uint_as_float(((unsigned)u) << 16);
}
__device__ __forceinline__ u16 f2bf(float f) {  // round-to-nearest-even
  unsigned u = __float_as_uint(f);
  return (u16)((u + 0x7fffu + ((u >> 16) & 1u)) >> 16);
}

// Write-through store (LLC-visible, bypasses the non-coherent per-XCD L2).
// Reads of h use PLAIN cached loads: every h address is fresh-per-t inside the
// kernel (one 1024B-aligned (b,t) row per set of lines), so reader L2s can't
// be stale; their miss pulls the sc1-written truth from LLC. Validated R6.
__device__ __forceinline__ void sth(u16* p, u16 v) {
  __hip_atomic_store(p, v, __ATOMIC_RELAXED, __HIP_MEMORY_SCOPE_AGENT);
}
__device__ __forceinline__ void stf(unsigned* p, unsigned v) {
  __hip_atomic_store(p, v, __ATOMIC_RELAXED, __HIP_MEMORY_SCOPE_AGENT);
}
__device__ __forceinline__ unsigned ldf(const unsigned* p) {
  return __hip_atomic_load(p, __ATOMIC_RELAXED, __HIP_MEMORY_SCOPE_AGENT);
}

// ---------------- workspace layout ----------------
// fp32 region (element offsets):
constexpr size_t F_B0P  = 0;                               // 2048
constexpr size_t F_B1P  = F_B0P  + 2048;                   // 2048
constexpr size_t F_WX0E = F_B1P  + 2048;                   // 4*2048
constexpr size_t F_PROJ = F_WX0E + 8192;                   // B*S*128
constexpr size_t F_SCORE= F_PROJ + (size_t)BB*SS*HH;       // B*S
constexpr size_t F_BAR  = F_SCORE+ (size_t)BB*SS;          // 8 groups x 32 flags
constexpr size_t F_END  = F_BAR  + 512;
// u16 (bf16) region, starts at byte F_END*4 (16B aligned):
constexpr size_t U_WB0  = 0;                               // 128*16*64*8
constexpr size_t U_WB1  = U_WB0 + (size_t)128*16*64*8;     // 128*32*64*8
constexpr size_t U_H1   = U_WB1 + (size_t)128*32*64*8;     // B*S*512
constexpr size_t U_H2   = U_H1  + (size_t)BB*SS*512;       // B*S*512
constexpr size_t U_END  = U_H2  + (size_t)BB*SS*512;
constexpr size_t NEED_BYTES = F_END*4 + U_END*2;

// ---------------- weight expansion into bf16 fragment-major ----------------
// WB[nt][ks][lane][e]: element W[k = ks*32 + (lane>>4)*8 + e][n' = nt*16 + (lane&15)]
__global__ __launch_bounds__(256)
void k_expand(const float* __restrict__ Wh0, const float* __restrict__ Wx1,
              const float* __restrict__ Wh1, const float* __restrict__ Wx0,
              const float* __restrict__ b0,  const float* __restrict__ b1,
              u16* __restrict__ WB0, u16* __restrict__ WB1,
              float* __restrict__ wx0e, float* __restrict__ b0p,
              float* __restrict__ b1p)
{
  const int idx = blockIdx.x*256 + threadIdx.x;   // 0 .. 2M-1 exactly
  { // WB1 (layer 1, K=1024: rows 0..511 = Wx1 on h1_t, 512..1023 = Wh1)
    const int e  = idx & 7;
    const int ln = (idx >> 3) & 63;
    const int ks = (idx >> 9) & 31;
    const int nt = idx >> 14;
    const int k  = ks*32 + (ln >> 4)*8 + e;
    const int np = nt*16 + (ln & 15);
    const int g  = (np >> 2) & 3, co = np & 3;
    const int o  = g*HH + nt;
    const int ci = k & 3;
    const int wi = c_widx[ci*4+co];
    const float sg = c_sgn[ci*4+co];
    const float wv = (k < 512)
      ? Wx1[((size_t)wi*HH + (k >> 2))*512 + o]
      : Wh1[((size_t)wi*HH + ((k - 512) >> 2))*512 + o];
    WB1[idx] = f2bf(sg*wv);
  }
  if (idx < 128*16*64*8) { // WB0 (layer 0 recurrent, K=512)
    const int e  = idx & 7;
    const int ln = (idx >> 3) & 63;
    const int ks = (idx >> 9) & 15;
    const int nt = idx >> 13;
    const int k  = ks*32 + (ln >> 4)*8 + e;
    const int np = nt*16 + (ln & 15);
    const int g  = (np >> 2) & 3, co = np & 3;
    const int o  = g*HH + nt;
    const int ci = k & 3;
    const int wi = c_widx[ci*4+co];
    const float sg = c_sgn[ci*4+co];
    WB0[idx] = f2bf(sg*Wh0[((size_t)wi*HH + (k >> 2))*512 + o]);
  }
  if (idx < 8192) { // wx0e[ci][n'] fp32 (layer-0 input proj, in=1)
    const int ci = idx >> 11, np = idx & 2047;
    const int m = np >> 4, g = (np >> 2) & 3, co = np & 3;
    const int o = g*HH + m;
    wx0e[idx] = c_sgn[ci*4+co]*Wx0[(size_t)c_widx[ci*4+co]*512 + o];
  }
  if (idx < 2048) { // permuted biases fp32
    const int np = idx;
    const int m = np >> 4, g = (np >> 2) & 3, co = np & 3;
    const int o = g*HH + m;
    b0p[idx] = b0[(size_t)o*4 + co];
    b1p[idx] = b1[(size_t)o*4 + co];
  }
}

__global__ __launch_bounds__(256)
void k_init(unsigned* __restrict__ bar)
{
  const int i = blockIdx.x*256 + threadIdx.x;
  if (i < 512) bar[i] = 0u;
}

// ---------------- O(1)-depth group barrier (flag array + parallel poll) ------
// Group = 32 blocks sharing one r0-tile; flags[grp][32] in one 128B line.
// Leader STOREs its slot (no RMW chain), wave 0 lanes 0-31 poll one slot each
// (one parallel LLC round-trip). h-store visibility: __syncthreads() drains
// vmcnt before the flag store; relaxed/sc1 everywhere (no L2 invalidates).
__device__ __forceinline__ void gbar(unsigned* flags, int slot, unsigned target)
{
  __syncthreads();                 // all waves' sc1 h-stores drained (vmcnt 0)
  if (threadIdx.x == 0) stf(&flags[slot], target);
  if (threadIdx.x < 32) {
    while (ldf(&flags[threadIdx.x]) < target)
      __builtin_amdgcn_s_sleep(1);
  }
  __syncthreads();
  asm volatile("" ::: "memory");   // no cached-read hoisting above the spin
}

// ---------------- persistent fused 2-layer LSTM ----------------
// 256 blocks x 512 threads (8 waves). XCD-aware mapping: xcd=bid&7 owns
// nt in [xcd*16, xcd*16+16) -> per-XCD weight slice ~768 KB (L2-resident).
// Waves 0-3: layer0 step t=n; waves 4-7: layer1 step t=n-1 (pipelined).
// Weights register-resident; cell state in 1 reg/lane.
__global__ __launch_bounds__(512, 1)
void k_lstm(const u16* __restrict__ WB0, const u16* __restrict__ WB1,
            const float* __restrict__ b0p, const float* __restrict__ b1p,
            const float* __restrict__ wx0e, const float* __restrict__ x,
            u16* __restrict__ h1, u16* __restrict__ h2,
            unsigned* __restrict__ bar)
{
  __shared__ float gs[8][16][17];
  const int tid = threadIdx.x;
  const int w   = tid >> 6;          // wave 0..7
  const int l   = tid & 63;
  const int bid = blockIdx.x;
  const int xcd = bid & 7;
  const int j   = bid >> 3;          // 0..31
  const int grp = j >> 2;            // r0-tile group 0..7
  const int jj  = j & 3;             // nt sub-slice 0..3
  const int r0  = grp*16;
  const int slot = xcd*4 + jj;       // 0..31 within group
  unsigned* flags = bar + grp*32;    // 128B line per group
  const int lrow = l & 15;
  const int lg   = l >> 4;
  const int row  = l >> 2, co = l & 3;
  float creg = 0.f;

  if (w < 4) {  // ---- layer 0 waves ----
    const int nt = xcd*16 + jj*4 + w;
    s16x8 wf[16];
    {
      const u16* wb = WB0 + ((size_t)nt*16*64 + l)*8;
      #pragma unroll
      for (int ks = 0; ks < 16; ++ks) wf[ks] = *(const s16x8*)(wb + (size_t)ks*512);
    }
    const float bv  = b0p[nt*16 + lrow];
    const float xw0 = wx0e[0*NG + nt*16 + lrow];
    const float xw1 = wx0e[1*NG + nt*16 + lrow];
    const float xw2 = wx0e[2*NG + nt*16 + lrow];
    const float xw3 = wx0e[3*NG + nt*16 + lrow];
    for (int n = 0; n <= SS; ++n) {
      if (n < SS) {
        const int t = n;
        f32x4 acc = {0.f, 0.f, 0.f, 0.f};
        if (t > 0) {
          const u16* ap = h1 + ((size_t)(r0 + lrow)*SS + (t - 1))*512 + lg*8;
          #pragma unroll
          for (int ks = 0; ks < 16; ++ks) {
            s16x8 a = *(const s16x8*)(ap + (size_t)ks*32);
            acc = __builtin_amdgcn_mfma_f32_16x16x32_bf16(a, wf[ks], acc, 0, 0, 0);
          }
        }
        #pragma unroll
        for (int r = 0; r < 4; ++r) {
          const int brow = r0 + lg*4 + r;
          const float4 xv = *(const float4*)&x[((size_t)brow*SS + t)*4];
          gs[w][lg*4 + r][lrow] = acc[r] + bv
            + xv.x*xw0 + xv.y*xw1 + xv.z*xw2 + xv.w*xw3;
        }
        // per-wave LDS transpose: no block barrier needed
        const float i_g = fsig (gs[w][row][0*4 + co]);
        const float f_g = fsig (gs[w][row][1*4 + co]);
        const float g_g = ftanh(gs[w][row][2*4 + co]);
        const float o_g = fsig (gs[w][row][3*4 + co]);
        creg = f_g*creg + i_g*g_g;
        const float hn = o_g*ftanh(creg);
        sth(&h1[((size_t)(r0 + row)*SS + t)*512 + nt*4 + co], f2bf(hn));
      }
      if (n < SS) gbar(flags, slot, (unsigned)n + 1u);
    }
  } else {      // ---- layer 1 waves ----
    const int nt = xcd*16 + jj*4 + (w - 4);
    s16x8 wf[32];
    {
      const u16* wb = WB1 + ((size_t)nt*32*64 + l)*8;
      #pragma unroll
      for (int ks = 0; ks < 32; ++ks) wf[ks] = *(const s16x8*)(wb + (size_t)ks*512);
    }
    const float bv = b1p[nt*16 + lrow];
    for (int n = 0; n <= SS; ++n) {
      if (n >= 1) {
        const int t = n - 1;
        f32x4 acc = {0.f, 0.f, 0.f, 0.f};
        {
          const u16* ap1 = h1 + ((size_t)(r0 + lrow)*SS + t)*512 + lg*8;
          #pragma unroll
          for (int ks = 0; ks < 16; ++ks) {
            s16x8 a = *(const s16x8*)(ap1 + (size_t)ks*32);
            acc = __builtin_amdgcn_mfma_f32_16x16x32_bf16(a, wf[ks], acc, 0, 0, 0);
          }
        }
        if (t > 0) {
          const u16* ap2 = h2 + ((size_t)(r0 + lrow)*SS + (t - 1))*512 + lg*8;
          #pragma unroll
          for (int ks = 0; ks < 16; ++ks) {
            s16x8 a = *(const s16x8*)(ap2 + (size_t)ks*32);
            acc = __builtin_amdgcn_mfma_f32_16x16x32_bf16(a, wf[16 + ks], acc, 0, 0, 0);
          }
        }
        #pragma unroll
        for (int r = 0; r < 4; ++r)
          gs[w][lg*4 + r][lrow] = acc[r] + bv;
        const float i_g = fsig (gs[w][row][0*4 + co]);
        const float f_g = fsig (gs[w][row][1*4 + co]);
        const float g_g = ftanh(gs[w][row][2*4 + co]);
        const float o_g = fsig (gs[w][row][3*4 + co]);
        creg = f_g*creg + i_g*g_g;
        const float hn = o_g*ftanh(creg);
        sth(&h2[((size_t)(r0 + row)*SS + t)*512 + nt*4 + co], f2bf(hn));
      }
      if (n < SS) gbar(flags, slot, (unsigned)n + 1u);
    }
  }
}

// ---------------- head: projected = h2flat @ Wp + bp ----------------
__global__ __launch_bounds__(256)
void k_proj(const u16* __restrict__ h2, const float* __restrict__ Wp,
            const float* __restrict__ bp, float* __restrict__ proj)
{
  __shared__ float hsh[8][512];
  const int tid = threadIdx.x;
  const int j   = tid & 127;
  const int rh  = tid >> 7;
  const size_t bs0 = (size_t)blockIdx.x * 8;
  for (int f = tid*8; f < 8*512; f += 2048) {
    const int lr = f >> 9, lc = f & 511;
    u16x8 rv = *(const u16x8*)&h2[(bs0 + lr)*512 + lc];
    float4 a, b;
    a.x=bf2f(rv[0]); a.y=bf2f(rv[1]); a.z=bf2f(rv[2]); a.w=bf2f(rv[3]);
    b.x=bf2f(rv[4]); b.y=bf2f(rv[5]); b.z=bf2f(rv[6]); b.w=bf2f(rv[7]);
    *(float4*)&hsh[lr][lc]   = a;
    *(float4*)&hsh[lr][lc+4] = b;
  }
  __syncthreads();
  const float bv = bp[j];
  float a0=bv, a1=bv, a2=bv, a3=bv;
  #pragma unroll 2
  for (int kk = 0; kk < 512; kk += 4) {
    const float w0 = Wp[(size_t)(kk+0)*HH + j];
    const float w1 = Wp[(size_t)(kk+1)*HH + j];
    const float w2 = Wp[(size_t)(kk+2)*HH + j];
    const float w3 = Wp[(size_t)(kk+3)*HH + j];
    const float4 h0 = *(const float4*)&hsh[rh*4+0][kk];
    const float4 h1 = *(const float4*)&hsh[rh*4+1][kk];
    const float4 h2v= *(const float4*)&hsh[rh*4+2][kk];
    const float4 h3 = *(const float4*)&hsh[rh*4+3][kk];
    a0 += h0.x*w0  + h0.y*w1  + h0.z*w2  + h0.w*w3;
    a1 += h1.x*w0  + h1.y*w1  + h1.z*w2  + h1.w*w3;
    a2 += h2v.x*w0 + h2v.y*w1 + h2v.z*w2 + h2v.w*w3;
    a3 += h3.x*w0  + h3.y*w1  + h3.z*w2  + h3.w*w3;
  }
  proj[(bs0 + rh*4+0)*HH + j] = a0;
  proj[(bs0 + rh*4+1)*HH + j] = a1;
  proj[(bs0 + rh*4+2)*HH + j] = a2;
  proj[(bs0 + rh*4+3)*HH + j] = a3;
}

// ---------------- head: scores = tanh(proj @ Wa + ba) @ va ----------------
__global__ __launch_bounds__(256)
void k_scores(const float* __restrict__ proj, const float* __restrict__ Wa,
              const float* __restrict__ ba, const float* __restrict__ va,
              float* __restrict__ scores)
{
  __shared__ float was[64*128];
  __shared__ float ps[32][128];
  __shared__ float red[4];
  const int tid = threadIdx.x;
  const size_t bs0 = (size_t)blockIdx.x * 32;
  for (int f = tid*4; f < 32*128; f += 1024) {
    const int lr = f >> 7, lc = f & 127;
    *(float4*)&ps[lr][lc] = *(const float4*)&proj[(bs0 + lr)*HH + lc];
  }
  const int j  = tid & 127;
  const int rh = tid >> 7;
  float yacc[16];
  const float bav = ba[j];
  #pragma unroll
  for (int rp = 0; rp < 16; ++rp) yacc[rp] = bav;
  for (int half = 0; half < 2; ++half) {
    __syncthreads();
    for (int f = tid*4; f < 64*128; f += 1024)
      *(float4*)&was[f] = *(const float4*)&Wa[(size_t)half*8192 + f];
    __syncthreads();
    for (int rp = 0; rp < 16; ++rp) {
      const int rrow = rp*2 + rh;
      float y = yacc[rp];
      #pragma unroll 8
      for (int i2 = 0; i2 < 64; ++i2)
        y += ps[rrow][half*64 + i2] * was[i2*128 + j];
      yacc[rp] = y;
    }
  }
  const float vav = va[j];
  for (int rp = 0; rp < 16; ++rp) {
    float y = ftanh(yacc[rp]) * vav;
    for (int off = 32; off > 0; off >>= 1) y += __shfl_down(y, off);
    __syncthreads();
    if ((tid & 63) == 0) red[tid >> 6] = y;
    __syncthreads();
    if (tid == 0) scores[bs0 + rp*2 + 0] = red[0] + red[1];
    if (tid == 1) scores[bs0 + rp*2 + 1] = red[2] + red[3];
  }
}

// ---------------- head: softmax + context + output ----------------
__global__ __launch_bounds__(256)
void k_final(const float* __restrict__ proj, const float* __restrict__ scores,
             const float* __restrict__ Wo, const float* __restrict__ bo,
             float* __restrict__ out)
{
  __shared__ float sc[512];
  __shared__ float red[4];
  __shared__ float ctx2[2][128];
  const int tid = threadIdx.x;
  const int b = blockIdx.x;
  *(float2*)&sc[tid*2] = *(const float2*)&scores[(size_t)b*SS + tid*2];
  __syncthreads();
  float m = fmaxf(sc[tid], sc[tid+256]);
  for (int off = 32; off > 0; off >>= 1) m = fmaxf(m, __shfl_down(m, off));
  if ((tid & 63) == 0) red[tid >> 6] = m;
  __syncthreads();
  const float M = fmaxf(fmaxf(red[0], red[1]), fmaxf(red[2], red[3]));
  __syncthreads();
  const float e0 = __expf(sc[tid]     - M);
  const float e1 = __expf(sc[tid+256] - M);
  sc[tid] = e0; sc[tid+256] = e1;
  float s = e0 + e1;
  for (int off = 32; off > 0; off >>= 1) s += __shfl_down(s, off);
  if ((tid & 63) == 0) red[tid >> 6] = s;
  __syncthreads();
  const float rinv = 1.f/(red[0] + red[1] + red[2] + red[3]);
  const int h  = tid & 127;
  const int sh = tid >> 7;
  float cp = 0.f;
  #pragma unroll 4
  for (int ssi = sh*256; ssi < sh*256 + 256; ++ssi)
    cp += sc[ssi]*proj[((size_t)b*SS + ssi)*HH + h];
  ctx2[sh][h] = cp;
  __syncthreads();
  if (tid < 128) {
    const float ctx = (ctx2[0][tid] + ctx2[1][tid])*rinv;
    float v = ctx*Wo[tid];
    for (int off = 32; off > 0; off >>= 1) v += __shfl_down(v, off);
    if ((tid & 63) == 0) red[tid >> 6] = v;
  }
  __syncthreads();
  if (tid == 0) out[b] = red[0] + red[1] + bo[0];
}

// ---------------- host ----------------
extern "C" void kernel_launch(void* const* d_in, const int* in_sizes, int n_in,
                              void* d_out, int out_size, void* d_ws, size_t ws_size,
                              hipStream_t stream)
{
  (void)in_sizes; (void)n_in; (void)out_size;
  const float* x   = (const float*)d_in[0];
  const float* Wx0 = (const float*)d_in[1];
  const float* Wh0 = (const float*)d_in[2];
  const float* b0  = (const float*)d_in[3];
  const float* Wx1 = (const float*)d_in[4];
  const float* Wh1 = (const float*)d_in[5];
  const float* b1  = (const float*)d_in[6];
  const float* Wp  = (const float*)d_in[7];
  const float* bp  = (const float*)d_in[8];
  const float* Wa  = (const float*)d_in[9];
  const float* ba  = (const float*)d_in[10];
  const float* va  = (const float*)d_in[11];
  const float* Wo  = (const float*)d_in[12];
  const float* bo  = (const float*)d_in[13];
  float* ws  = (float*)d_ws;
  u16*   wsu = (u16*)((char*)d_ws + F_END*4);

  if (ws_size < NEED_BYTES) {
    fprintf(stderr, "[qnn] ws too small: have=%zu need=%zu\n", ws_size, NEED_BYTES);
    return;
  }

  k_expand<<<8192, 256, 0, stream>>>(Wh0, Wx1, Wh1, Wx0, b0, b1,
                                     wsu + U_WB0, wsu + U_WB1,
                                     ws + F_WX0E, ws + F_B0P, ws + F_B1P);
  k_init<<<2, 256, 0, stream>>>((unsigned*)(ws + F_BAR));

  k_lstm<<<256, 512, 0, stream>>>(wsu + U_WB0, wsu + U_WB1,
                                  ws + F_B0P, ws + F_B1P, ws + F_WX0E, x,
                                  wsu + U_H1, wsu + U_H2,
                                  (unsigned*)(ws + F_BAR));

  k_proj  <<<BB*SS/8,  256, 0, stream>>>(wsu + U_H2, Wp, bp, ws + F_PROJ);
  k_scores<<<BB*SS/32, 256, 0, stream>>>(ws + F_PROJ, Wa, ba, va, ws + F_SCORE);
  k_final <<<BB,       256, 0, stream>>>(ws + F_PROJ, ws + F_SCORE, Wo, bo,
                                         (float*)d_out);
}

// Round 9
// 4117.336 us; speedup vs baseline: 5.3466x; 1.1744x over previous
//
#include <hip/hip_runtime.h>
#include <cstdio>
#include <cstddef>

#define BB 128
#define SS 512
#define HH 128
#define NG 2048   // 4H*4 components, permuted column layout n' = m*16 + g*4 + co

typedef unsigned short u16;
typedef __attribute__((ext_vector_type(8))) u16   u16x8;
typedef __attribute__((ext_vector_type(8))) short s16x8;
typedef __attribute__((ext_vector_type(4))) float f32x4;

__constant__ int   c_widx[16] = {0,1,2,3, 1,0,3,2, 2,3,0,1, 3,2,1,0};
__constant__ float c_sgn [16] = {1.f,1.f,1.f,1.f, -1.f,1.f,-1.f,1.f,
                                 -1.f,1.f,1.f,-1.f, -1.f,-1.f,1.f,1.f};

__device__ __forceinline__ float fsig(float x) { return 1.f/(1.f + __expf(-x)); }
__device__ __forceinline__ float ftanh(float x) {
  float ax = fabsf(x);
  float e  = __expf(-2.f*ax);
  float tt = (1.f - e)/(1.f + e);
  return copysignf(tt, x);
}
__device__ __forceinline__ float bf2f(u16 u) {
  return __uint_as_float(((unsigned)u) << 16);
}
__device__ __forceinline__ u16 f2bf(float f) {  // round-to-nearest-even
  unsigned u = __float_as_uint(f);
  return (u16)((u + 0x7fffu + ((u >> 16) & 1u)) >> 16);
}

// Write-through stores (LLC-visible, bypass the non-coherent per-XCD L2).
// Reads of h use PLAIN cached loads: every h address is fresh-per-t inside the
// kernel, so reader L2s can't hold stale copies; their miss pulls the
// sc1-written truth from LLC. Scheme validated R6/R7 (bit-identical absmax).
__device__ __forceinline__ void st4(unsigned* p, unsigned v) {
  __hip_atomic_store(p, v, __ATOMIC_RELAXED, __HIP_MEMORY_SCOPE_AGENT);
}
__device__ __forceinline__ unsigned ldf(const unsigned* p) {
  return __hip_atomic_load(p, __ATOMIC_RELAXED, __HIP_MEMORY_SCOPE_AGENT);
}

// ---------------- workspace layout ----------------
// fp32 region (element offsets):
constexpr size_t F_B0P  = 0;                               // 2048
constexpr size_t F_B1P  = F_B0P  + 2048;                   // 2048
constexpr size_t F_WX0E = F_B1P  + 2048;                   // 4*2048
constexpr size_t F_PROJ = F_WX0E + 8192;                   // B*S*128
constexpr size_t F_SCORE= F_PROJ + (size_t)BB*SS*HH;       // B*S
constexpr size_t F_BAR  = F_SCORE+ (size_t)BB*SS;          // 8 groups x 32 flags
constexpr size_t F_END  = F_BAR  + 512;
// u16 (bf16) region, starts at byte F_END*4 (16B aligned):
constexpr size_t U_WB0  = 0;                               // 128*16*64*8
constexpr size_t U_WB1  = U_WB0 + (size_t)128*16*64*8;     // 128*32*64*8
constexpr size_t U_H1   = U_WB1 + (size_t)128*32*64*8;     // S*B*512 ([t][b][n'])
constexpr size_t U_H2   = U_H1  + (size_t)BB*SS*512;       // S*B*512 ([t][b][n'])
constexpr size_t U_END  = U_H2  + (size_t)BB*SS*512;
constexpr size_t NEED_BYTES = F_END*4 + U_END*2;

// ---------------- weight expansion into bf16 fragment-major ----------------
// WB[nt][ks][lane][e]: element W[k = ks*32 + (lane>>4)*8 + e][n' = nt*16 + (lane&15)]
__global__ __launch_bounds__(256)
void k_expand(const float* __restrict__ Wh0, const float* __restrict__ Wx1,
              const float* __restrict__ Wh1, const float* __restrict__ Wx0,
              const float* __restrict__ b0,  const float* __restrict__ b1,
              u16* __restrict__ WB0, u16* __restrict__ WB1,
              float* __restrict__ wx0e, float* __restrict__ b0p,
              float* __restrict__ b1p)
{
  const int idx = blockIdx.x*256 + threadIdx.x;   // 0 .. 2M-1 exactly
  { // WB1 (layer 1, K=1024: rows 0..511 = Wx1 on h1_t, 512..1023 = Wh1)
    const int e  = idx & 7;
    const int ln = (idx >> 3) & 63;
    const int ks = (idx >> 9) & 31;
    const int nt = idx >> 14;
    const int k  = ks*32 + (ln >> 4)*8 + e;
    const int np = nt*16 + (ln & 15);
    const int g  = (np >> 2) & 3, co = np & 3;
    const int o  = g*HH + nt;
    const int ci = k & 3;
    const int wi = c_widx[ci*4+co];
    const float sg = c_sgn[ci*4+co];
    const float wv = (k < 512)
      ? Wx1[((size_t)wi*HH + (k >> 2))*512 + o]
      : Wh1[((size_t)wi*HH + ((k - 512) >> 2))*512 + o];
    WB1[idx] = f2bf(sg*wv);
  }
  if (idx < 128*16*64*8) { // WB0 (layer 0 recurrent, K=512)
    const int e  = idx & 7;
    const int ln = (idx >> 3) & 63;
    const int ks = (idx >> 9) & 15;
    const int nt = idx >> 13;
    const int k  = ks*32 + (ln >> 4)*8 + e;
    const int np = nt*16 + (ln & 15);
    const int g  = (np >> 2) & 3, co = np & 3;
    const int o  = g*HH + nt;
    const int ci = k & 3;
    const int wi = c_widx[ci*4+co];
    const float sg = c_sgn[ci*4+co];
    WB0[idx] = f2bf(sg*Wh0[((size_t)wi*HH + (k >> 2))*512 + o]);
  }
  if (idx < 8192) { // wx0e[ci][n'] fp32 (layer-0 input proj, in=1)
    const int ci = idx >> 11, np = idx & 2047;
    const int m = np >> 4, g = (np >> 2) & 3, co = np & 3;
    const int o = g*HH + m;
    wx0e[idx] = c_sgn[ci*4+co]*Wx0[(size_t)c_widx[ci*4+co]*512 + o];
  }
  if (idx < 2048) { // permuted biases fp32
    const int np = idx;
    const int m = np >> 4, g = (np >> 2) & 3, co = np & 3;
    const int o = g*HH + m;
    b0p[idx] = b0[(size_t)o*4 + co];
    b1p[idx] = b1[(size_t)o*4 + co];
  }
}

__global__ __launch_bounds__(256)
void k_init(unsigned* __restrict__ bar)
{
  const int i = blockIdx.x*256 + threadIdx.x;
  if (i < 512) bar[i] = 0u;
}

// ---------------- O(1)-depth group barrier (flag array + parallel poll) ------
// Group = 32 blocks sharing one r0-tile; flags[grp][32] in one 128B line.
// Leader STOREs its slot (no RMW chain), wave 0 lanes 0-31 poll one slot each.
// h-store visibility: __syncthreads() drains vmcnt before the flag store;
// relaxed/sc1 everywhere (no L2 invalidates). Validated R7.
__device__ __forceinline__ void gbar(unsigned* flags, int slot, unsigned target)
{
  __syncthreads();                 // all waves' sc1 h-stores drained (vmcnt 0)
  if (threadIdx.x == 0) st4(&flags[slot], target);
  if (threadIdx.x < 32) {
    while (ldf(&flags[threadIdx.x]) < target)
      __builtin_amdgcn_s_sleep(1);
  }
  __syncthreads();
  asm volatile("" ::: "memory");   // no cached-read hoisting above the spin
}

// ---------------- persistent fused 2-layer LSTM ----------------
// 256 blocks x 512 threads (8 waves). Group = bid&7 (32 blocks, likely one
// XCD under round-robin dispatch -> group's h rows fetched into ONE L2, not 8;
// a different mapping only costs speed, never correctness). h layout [t][b][n']
// so each step slice is a contiguous 128KB block. Waves 0-3: layer0 t=n;
// waves 4-7: layer1 t=n-1 (pipelined). Weights register-resident.
__global__ __launch_bounds__(512, 1)
void k_lstm(const u16* __restrict__ WB0, const u16* __restrict__ WB1,
            const float* __restrict__ b0p, const float* __restrict__ b1p,
            const float* __restrict__ wx0e, const float* __restrict__ x,
            u16* __restrict__ h1, u16* __restrict__ h2,
            unsigned* __restrict__ bar)
{
  __shared__ float gs[8][16][17];
  const int tid = threadIdx.x;
  const int w   = tid >> 6;          // wave 0..7
  const int l   = tid & 63;
  const int bid = blockIdx.x;
  const int grp = bid & 7;           // r0-tile group (XCD-coherent under %8 map)
  const int j2  = bid >> 3;          // 0..31: nt slice + barrier slot
  const int r0  = grp*16;
  const int slot = j2;
  unsigned* flags = bar + grp*32;    // one 128B line per group
  const int lrow = l & 15;
  const int lg   = l >> 4;
  float creg0 = 0.f, creg1 = 0.f;    // 2 cell states/thread (paired epilogue)

  if (w < 4) {  // ---- layer 0 waves ----
    const int nt = j2*4 + w;
    s16x8 wf[16];
    {
      const u16* wb = WB0 + ((size_t)nt*16*64 + l)*8;
      #pragma unroll
      for (int ks = 0; ks < 16; ++ks) wf[ks] = *(const s16x8*)(wb + (size_t)ks*512);
    }
    const float bv  = b0p[nt*16 + lrow];
    const float xw0 = wx0e[0*NG + nt*16 + lrow];
    const float xw1 = wx0e[1*NG + nt*16 + lrow];
    const float xw2 = wx0e[2*NG + nt*16 + lrow];
    const float xw3 = wx0e[3*NG + nt*16 + lrow];
    for (int n = 0; n <= SS; ++n) {
      if (n < SS) {
        const int t = n;
        f32x4 acc = {0.f, 0.f, 0.f, 0.f};
        if (t > 0) {
          const u16* ap = h1 + ((size_t)(t - 1)*BB + (r0 + lrow))*512 + lg*8;
          #pragma unroll
          for (int ks = 0; ks < 16; ++ks) {
            s16x8 a = *(const s16x8*)(ap + (size_t)ks*32);
            acc = __builtin_amdgcn_mfma_f32_16x16x32_bf16(a, wf[ks], acc, 0, 0, 0);
          }
        }
        #pragma unroll
        for (int r = 0; r < 4; ++r) {
          const int brow = r0 + lg*4 + r;
          const float4 xv = *(const float4*)&x[((size_t)brow*SS + t)*4];
          gs[w][lg*4 + r][lrow] = acc[r] + bv
            + xv.x*xw0 + xv.y*xw1 + xv.z*xw2 + xv.w*xw3;
        }
        // per-wave LDS transpose (wave-synchronous); paired cell update
        if (l < 32) {
          const int row = l >> 1, cp = l & 1;
          const int c0 = cp*2, c1 = cp*2 + 1;
          const float i0 = fsig (gs[w][row][0*4 + c0]);
          const float i1 = fsig (gs[w][row][0*4 + c1]);
          const float f0 = fsig (gs[w][row][1*4 + c0]);
          const float f1 = fsig (gs[w][row][1*4 + c1]);
          const float g0 = ftanh(gs[w][row][2*4 + c0]);
          const float g1 = ftanh(gs[w][row][2*4 + c1]);
          const float o0 = fsig (gs[w][row][3*4 + c0]);
          const float o1 = fsig (gs[w][row][3*4 + c1]);
          creg0 = f0*creg0 + i0*g0;
          creg1 = f1*creg1 + i1*g1;
          const unsigned pk = (unsigned)f2bf(o0*ftanh(creg0))
                            | ((unsigned)f2bf(o1*ftanh(creg1)) << 16);
          unsigned* dst = (unsigned*)&h1[((size_t)t*BB + (r0 + row))*512 + nt*4 + cp*2];
          st4(dst, pk);
        }
      }
      if (n < SS) gbar(flags, slot, (unsigned)n + 1u);
    }
  } else {      // ---- layer 1 waves ----
    const int nt = j2*4 + (w - 4);
    s16x8 wf[32];
    {
      const u16* wb = WB1 + ((size_t)nt*32*64 + l)*8;
      #pragma unroll
      for (int ks = 0; ks < 32; ++ks) wf[ks] = *(const s16x8*)(wb + (size_t)ks*512);
    }
    const float bv = b1p[nt*16 + lrow];
    for (int n = 0; n <= SS; ++n) {
      if (n >= 1) {
        const int t = n - 1;
        f32x4 acc = {0.f, 0.f, 0.f, 0.f};
        {
          const u16* ap1 = h1 + ((size_t)t*BB + (r0 + lrow))*512 + lg*8;
          #pragma unroll
          for (int ks = 0; ks < 16; ++ks) {
            s16x8 a = *(const s16x8*)(ap1 + (size_t)ks*32);
            acc = __builtin_amdgcn_mfma_f32_16x16x32_bf16(a, wf[ks], acc, 0, 0, 0);
          }
        }
        if (t > 0) {
          const u16* ap2 = h2 + ((size_t)(t - 1)*BB + (r0 + lrow))*512 + lg*8;
          #pragma unroll
          for (int ks = 0; ks < 16; ++ks) {
            s16x8 a = *(const s16x8*)(ap2 + (size_t)ks*32);
            acc = __builtin_amdgcn_mfma_f32_16x16x32_bf16(a, wf[16 + ks], acc, 0, 0, 0);
          }
        }
        #pragma unroll
        for (int r = 0; r < 4; ++r)
          gs[w][lg*4 + r][lrow] = acc[r] + bv;
        if (l < 32) {
          const int row = l >> 1, cp = l & 1;
          const int c0 = cp*2, c1 = cp*2 + 1;
          const float i0 = fsig (gs[w][row][0*4 + c0]);
          const float i1 = fsig (gs[w][row][0*4 + c1]);
          const float f0 = fsig (gs[w][row][1*4 + c0]);
          const float f1 = fsig (gs[w][row][1*4 + c1]);
          const float g0 = ftanh(gs[w][row][2*4 + c0]);
          const float g1 = ftanh(gs[w][row][2*4 + c1]);
          const float o0 = fsig (gs[w][row][3*4 + c0]);
          const float o1 = fsig (gs[w][row][3*4 + c1]);
          creg0 = f0*creg0 + i0*g0;
          creg1 = f1*creg1 + i1*g1;
          const unsigned pk = (unsigned)f2bf(o0*ftanh(creg0))
                            | ((unsigned)f2bf(o1*ftanh(creg1)) << 16);
          unsigned* dst = (unsigned*)&h2[((size_t)t*BB + (r0 + row))*512 + nt*4 + cp*2];
          st4(dst, pk);
        }
      }
      if (n < SS) gbar(flags, slot, (unsigned)n + 1u);
    }
  }
}

// ---------------- head: projected = h2flat @ Wp + bp ----------------
// h2 layout [t][b][512]; flat row fr = t*BB + b. proj stays (b*SS + s) order.
__global__ __launch_bounds__(256)
void k_proj(const u16* __restrict__ h2, const float* __restrict__ Wp,
            const float* __restrict__ bp, float* __restrict__ proj)
{
  __shared__ float hsh[8][512];
  const int tid = threadIdx.x;
  const int j   = tid & 127;
  const int rh  = tid >> 7;
  const size_t fr0 = (size_t)blockIdx.x * 8;
  for (int f = tid*8; f < 8*512; f += 2048) {
    const int lr = f >> 9, lc = f & 511;
    u16x8 rv = *(const u16x8*)&h2[(fr0 + lr)*512 + lc];
    float4 a, b;
    a.x=bf2f(rv[0]); a.y=bf2f(rv[1]); a.z=bf2f(rv[2]); a.w=bf2f(rv[3]);
    b.x=bf2f(rv[4]); b.y=bf2f(rv[5]); b.z=bf2f(rv[6]); b.w=bf2f(rv[7]);
    *(float4*)&hsh[lr][lc]   = a;
    *(float4*)&hsh[lr][lc+4] = b;
  }
  __syncthreads();
  const float bv = bp[j];
  float a0=bv, a1=bv, a2=bv, a3=bv;
  #pragma unroll 2
  for (int kk = 0; kk < 512; kk += 4) {
    const float w0 = Wp[(size_t)(kk+0)*HH + j];
    const float w1 = Wp[(size_t)(kk+1)*HH + j];
    const float w2 = Wp[(size_t)(kk+2)*HH + j];
    const float w3 = Wp[(size_t)(kk+3)*HH + j];
    const float4 h0 = *(const float4*)&hsh[rh*4+0][kk];
    const float4 h1 = *(const float4*)&hsh[rh*4+1][kk];
    const float4 h2v= *(const float4*)&hsh[rh*4+2][kk];
    const float4 h3 = *(const float4*)&hsh[rh*4+3][kk];
    a0 += h0.x*w0  + h0.y*w1  + h0.z*w2  + h0.w*w3;
    a1 += h1.x*w0  + h1.y*w1  + h1.z*w2  + h1.w*w3;
    a2 += h2v.x*w0 + h2v.y*w1 + h2v.z*w2 + h2v.w*w3;
    a3 += h3.x*w0  + h3.y*w1  + h3.z*w2  + h3.w*w3;
  }
  #pragma unroll
  for (int q = 0; q < 4; ++q) {
    const size_t fr = fr0 + rh*4 + q;
    const int bb = (int)(fr & 127);
    const int ss2 = (int)(fr >> 7);
    const float v = (q == 0) ? a0 : (q == 1) ? a1 : (q == 2) ? a2 : a3;
    proj[((size_t)bb*SS + ss2)*HH + j] = v;
  }
}

// ---------------- head: scores = tanh(proj @ Wa + ba) @ va ----------------
__global__ __launch_bounds__(256)
void k_scores(const float* __restrict__ proj, const float* __restrict__ Wa,
              const float* __restrict__ ba, const float* __restrict__ va,
              float* __restrict__ scores)
{
  __shared__ float was[64*128];
  __shared__ float ps[32][128];
  __shared__ float red[4];
  const int tid = threadIdx.x;
  const size_t bs0 = (size_t)blockIdx.x * 32;
  for (int f = tid*4; f < 32*128; f += 1024) {
    const int lr = f >> 7, lc = f & 127;
    *(float4*)&ps[lr][lc] = *(const float4*)&proj[(bs0 + lr)*HH + lc];
  }
  const int j  = tid & 127;
  const int rh = tid >> 7;
  float yacc[16];
  const float bav = ba[j];
  #pragma unroll
  for (int rp = 0; rp < 16; ++rp) yacc[rp] = bav;
  for (int half = 0; half < 2; ++half) {
    __syncthreads();
    for (int f = tid*4; f < 64*128; f += 1024)
      *(float4*)&was[f] = *(const float4*)&Wa[(size_t)half*8192 + f];
    __syncthreads();
    for (int rp = 0; rp < 16; ++rp) {
      const int rrow = rp*2 + rh;
      float y = yacc[rp];
      #pragma unroll 8
      for (int i2 = 0; i2 < 64; ++i2)
        y += ps[rrow][half*64 + i2] * was[i2*128 + j];
      yacc[rp] = y;
    }
  }
  const float vav = va[j];
  for (int rp = 0; rp < 16; ++rp) {
    float y = ftanh(yacc[rp]) * vav;
    for (int off = 32; off > 0; off >>= 1) y += __shfl_down(y, off);
    __syncthreads();
    if ((tid & 63) == 0) red[tid >> 6] = y;
    __syncthreads();
    if (tid == 0) scores[bs0 + rp*2 + 0] = red[0] + red[1];
    if (tid == 1) scores[bs0 + rp*2 + 1] = red[2] + red[3];
  }
}

// ---------------- head: softmax + context + output ----------------
__global__ __launch_bounds__(256)
void k_final(const float* __restrict__ proj, const float* __restrict__ scores,
             const float* __restrict__ Wo, const float* __restrict__ bo,
             float* __restrict__ out)
{
  __shared__ float sc[512];
  __shared__ float red[4];
  __shared__ float ctx2[2][128];
  const int tid = threadIdx.x;
  const int b = blockIdx.x;
  *(float2*)&sc[tid*2] = *(const float2*)&scores[(size_t)b*SS + tid*2];
  __syncthreads();
  float m = fmaxf(sc[tid], sc[tid+256]);
  for (int off = 32; off > 0; off >>= 1) m = fmaxf(m, __shfl_down(m, off));
  if ((tid & 63) == 0) red[tid >> 6] = m;
  __syncthreads();
  const float M = fmaxf(fmaxf(red[0], red[1]), fmaxf(red[2], red[3]));
  __syncthreads();
  const float e0 = __expf(sc[tid]     - M);
  const float e1 = __expf(sc[tid+256] - M);
  sc[tid] = e0; sc[tid+256] = e1;
  float s = e0 + e1;
  for (int off = 32; off > 0; off >>= 1) s += __shfl_down(s, off);
  if ((tid & 63) == 0) red[tid >> 6] = s;
  __syncthreads();
  const float rinv = 1.f/(red[0] + red[1] + red[2] + red[3]);
  const int h  = tid & 127;
  const int sh = tid >> 7;
  float cp = 0.f;
  #pragma unroll 4
  for (int ssi = sh*256; ssi < sh*256 + 256; ++ssi)
    cp += sc[ssi]*proj[((size_t)b*SS + ssi)*HH + h];
  ctx2[sh][h] = cp;
  __syncthreads();
  if (tid < 128) {
    const float ctx = (ctx2[0][tid] + ctx2[1][tid])*rinv;
    float v = ctx*Wo[tid];
    for (int off = 32; off > 0; off >>= 1) v += __shfl_down(v, off);
    if ((tid & 63) == 0) red[tid >> 6] = v;
  }
  __syncthreads();
  if (tid == 0) out[b] = red[0] + red[1] + bo[0];
}

// ---------------- host ----------------
extern "C" void kernel_launch(void* const* d_in, const int* in_sizes, int n_in,
                              void* d_out, int out_size, void* d_ws, size_t ws_size,
                              hipStream_t stream)
{
  (void)in_sizes; (void)n_in; (void)out_size;
  const float* x   = (const float*)d_in[0];
  const float* Wx0 = (const float*)d_in[1];
  const float* Wh0 = (const float*)d_in[2];
  const float* b0  = (const float*)d_in[3];
  const float* Wx1 = (const float*)d_in[4];
  const float* Wh1 = (const float*)d_in[5];
  const float* b1  = (const float*)d_in[6];
  const float* Wp  = (const float*)d_in[7];
  const float* bp  = (const float*)d_in[8];
  const float* Wa  = (const float*)d_in[9];
  const float* ba  = (const float*)d_in[10];
  const float* va  = (const float*)d_in[11];
  const float* Wo  = (const float*)d_in[12];
  const float* bo  = (const float*)d_in[13];
  float* ws  = (float*)d_ws;
  u16*   wsu = (u16*)((char*)d_ws + F_END*4);

  if (ws_size < NEED_BYTES) {
    fprintf(stderr, "[qnn] ws too small: have=%zu need=%zu\n", ws_size, NEED_BYTES);
    return;
  }

  k_expand<<<8192, 256, 0, stream>>>(Wh0, Wx1, Wh1, Wx0, b0, b1,
                                     wsu + U_WB0, wsu + U_WB1,
                                     ws + F_WX0E, ws + F_B0P, ws + F_B1P);
  k_init<<<2, 256, 0, stream>>>((unsigned*)(ws + F_BAR));

  k_lstm<<<256, 512, 0, stream>>>(wsu + U_WB0, wsu + U_WB1,
                                  ws + F_B0P, ws + F_B1P, ws + F_WX0E, x,
                                  wsu + U_H1, wsu + U_H2,
                                  (unsigned*)(ws + F_BAR));

  k_proj  <<<BB*SS/8,  256, 0, stream>>>(wsu + U_H2, Wp, bp, ws + F_PROJ);
  k_scores<<<BB*SS/32, 256, 0, stream>>>(ws + F_PROJ, Wa, ba, va, ws + F_SCORE);
  k_final <<<BB,       256, 0, stream>>>(ws + F_PROJ, ws + F_SCORE, Wo, bo,
                                         (float*)d_out);
}

// Round 11
// 3505.149 us; speedup vs baseline: 6.2804x; 1.1747x over previous
//
#include <hip/hip_runtime.h>
#include <cstdio>
#include <cstddef>

#define BB 128
#define SS 512
#define HH 128
#define NG 2048   // 4H*4 components, permuted column layout n' = m*16 + g*4 + co

typedef unsigned short u16;
typedef unsigned int   u32;
typedef unsigned long long u64;
typedef __attribute__((ext_vector_type(8))) u16   u16x8;
typedef __attribute__((ext_vector_type(8))) short s16x8;
typedef __attribute__((ext_vector_type(4))) float f32x4;

__constant__ int   c_widx[16] = {0,1,2,3, 1,0,3,2, 2,3,0,1, 3,2,1,0};
__constant__ float c_sgn [16] = {1.f,1.f,1.f,1.f, -1.f,1.f,-1.f,1.f,
                                 -1.f,1.f,1.f,-1.f, -1.f,-1.f,1.f,1.f};

__device__ __forceinline__ float fsig(float x) { return 1.f/(1.f + __expf(-x)); }
__device__ __forceinline__ float ftanh(float x) {
  float ax = fabsf(x);
  float e  = __expf(-2.f*ax);
  float tt = (1.f - e)/(1.f + e);
  return copysignf(tt, x);
}
__device__ __forceinline__ float bf2f(u16 u) {
  return __uint_as_float(((unsigned)u) << 16);
}
__device__ __forceinline__ u16 f2bf(float f) {  // round-to-nearest-even
  unsigned u = __float_as_uint(f);
  return (u16)((u + 0x7fffu + ((u >> 16) & 1u)) >> 16);
}

// sc1 (LLC write-through, bypasses the non-coherent per-XCD L2) — the
// R6/R7/R9-validated protocol. Reads of h use PLAIN cached loads: every h
// address is fresh-per-t inside the kernel, so reader caches can't be stale;
// their miss pulls the sc1-written truth from LLC.
__device__ __forceinline__ void st4(u32* p, u32 v) {
  __hip_atomic_store(p, v, __ATOMIC_RELAXED, __HIP_MEMORY_SCOPE_AGENT);
}
__device__ __forceinline__ void st8(u64* p, u64 v) {
  __hip_atomic_store(p, v, __ATOMIC_RELAXED, __HIP_MEMORY_SCOPE_AGENT);
}
__device__ __forceinline__ u32 ldf(const u32* p) {
  return __hip_atomic_load(p, __ATOMIC_RELAXED, __HIP_MEMORY_SCOPE_AGENT);
}

// ---------------- workspace layout ----------------
constexpr size_t F_B0P  = 0;                               // 2048
constexpr size_t F_B1P  = F_B0P  + 2048;                   // 2048
constexpr size_t F_WX0E = F_B1P  + 2048;                   // 4*2048
constexpr size_t F_PROJ = F_WX0E + 8192;                   // B*S*128
constexpr size_t F_SCORE= F_PROJ + (size_t)BB*SS*HH;       // B*S
constexpr size_t F_BAR  = F_SCORE+ (size_t)BB*SS;          // 8 groups x 32 flags
constexpr size_t F_END  = F_BAR  + 512;
// u16 region, starts at byte F_END*4:
constexpr size_t U_WB0  = 0;                               // 128*16*64*8
constexpr size_t U_WB1  = U_WB0 + (size_t)128*16*64*8;     // 128*32*64*8
constexpr size_t U_H1   = U_WB1 + (size_t)128*32*64*8;     // [t][j2][b][16]
constexpr size_t U_H2   = U_H1  + (size_t)BB*SS*512;
constexpr size_t U_END  = U_H2  + (size_t)BB*SS*512;
constexpr size_t NEED_BYTES = F_END*4 + U_END*2;
// h address (u16 units): t*65536 + (k>>4)*2048 + b*16 + (k&15), k = m*4+co

// ---------------- weight expansion into bf16 fragment-major ----------------
// WB[nt][ks][lane][e]: element W[k = ks*32 + (lane>>4)*8 + e][n' = nt*16 + (lane&15)]
__global__ __launch_bounds__(256)
void k_expand(const float* __restrict__ Wh0, const float* __restrict__ Wx1,
              const float* __restrict__ Wh1, const float* __restrict__ Wx0,
              const float* __restrict__ b0,  const float* __restrict__ b1,
              u16* __restrict__ WB0, u16* __restrict__ WB1,
              float* __restrict__ wx0e, float* __restrict__ b0p,
              float* __restrict__ b1p)
{
  const int idx = blockIdx.x*256 + threadIdx.x;   // 0 .. 2M-1 exactly
  { // WB1 (layer 1, K=1024: rows 0..511 = Wx1 on h1_t, 512..1023 = Wh1)
    const int e  = idx & 7;
    const int ln = (idx >> 3) & 63;
    const int ks = (idx >> 9) & 31;
    const int nt = idx >> 14;
    const int k  = ks*32 + (ln >> 4)*8 + e;
    const int np = nt*16 + (ln & 15);
    const int g  = (np >> 2) & 3, co = np & 3;
    const int o  = g*HH + nt;
    const int ci = k & 3;
    const int wi = c_widx[ci*4+co];
    const float sg = c_sgn[ci*4+co];
    const float wv = (k < 512)
      ? Wx1[((size_t)wi*HH + (k >> 2))*512 + o]
      : Wh1[((size_t)wi*HH + ((k - 512) >> 2))*512 + o];
    WB1[idx] = f2bf(sg*wv);
  }
  if (idx < 128*16*64*8) { // WB0 (layer 0 recurrent, K=512)
    const int e  = idx & 7;
    const int ln = (idx >> 3) & 63;
    const int ks = (idx >> 9) & 15;
    const int nt = idx >> 13;
    const int k  = ks*32 + (ln >> 4)*8 + e;
    const int np = nt*16 + (ln & 15);
    const int g  = (np >> 2) & 3, co = np & 3;
    const int o  = g*HH + nt;
    const int ci = k & 3;
    const int wi = c_widx[ci*4+co];
    const float sg = c_sgn[ci*4+co];
    WB0[idx] = f2bf(sg*Wh0[((size_t)wi*HH + (k >> 2))*512 + o]);
  }
  if (idx < 8192) { // wx0e[ci][n'] fp32 (layer-0 input proj, in=1)
    const int ci = idx >> 11, np = idx & 2047;
    const int m = np >> 4, g = (np >> 2) & 3, co = np & 3;
    const int o = g*HH + m;
    wx0e[idx] = c_sgn[ci*4+co]*Wx0[(size_t)c_widx[ci*4+co]*512 + o];
  }
  if (idx < 2048) { // permuted biases fp32
    const int np = idx;
    const int m = np >> 4, g = (np >> 2) & 3, co = np & 3;
    const int o = g*HH + m;
    b0p[idx] = b0[(size_t)o*4 + co];
    b1p[idx] = b1[(size_t)o*4 + co];
  }
}

__global__ __launch_bounds__(256)
void k_init(u32* __restrict__ bar)
{
  const int i = blockIdx.x*256 + threadIdx.x;
  if (i < 512) bar[i] = 0u;
}

// ---------------- persistent fused 2-layer LSTM ----------------
// 256 blocks x 512 threads (8 waves). Group = bid&7 (32 blocks sharing batch
// rows r0=grp*16; under round-robin dispatch these co-locate on one XCD which
// is a pure SPEED effect — correctness only uses sc1/LLC). h layout
// [t][j2][b][16]: each block's per-step output = 512B contiguous, exclusively
// owned. Waves 0-3: layer0 t=n; waves 4-7: layer1 t=n-1 (pipelined).
// Wave 0 publishes both layers with lane-consecutive (coalescing) 8B sc1
// stores, then stores its flag and polls all 32 group flags in parallel.
__global__ __launch_bounds__(512, 1)
void k_lstm(const u16* __restrict__ WB0, const u16* __restrict__ WB1,
            const float* __restrict__ b0p, const float* __restrict__ b1p,
            const float* __restrict__ wx0e, const float* __restrict__ x,
            u16* __restrict__ h1, u16* __restrict__ h2,
            u32* __restrict__ bar)
{
  __shared__ float gs[8][16][17];
  __shared__ u32   stg[2][16][8];
  const int tid = threadIdx.x;
  const int bid = blockIdx.x;
  const int grp = bid & 7;           // r0-tile group
  const int j2  = bid >> 3;          // k-slice 0..31 = barrier slot
  const int r0  = grp*16;
  u32* flags = bar + grp*32;         // one 128B line per group

  const int w    = tid >> 6;         // wave 0..7
  const int l    = tid & 63;
  const int lrow = l & 15;
  const int lg   = l >> 4;
  // A-fragment address component for k = ks*32 + lg*8 + e in [t][j2][b][16]:
  const size_t laneoff = (size_t)(lg >> 1)*2048 + (size_t)(r0 + lrow)*16
                       + (size_t)(lg & 1)*8;
  const int ntl = j2*4 + (w & 3);
  float creg0 = 0.f, creg1 = 0.f;

  s16x8 wf[32];
  if (w < 4) {
    const u16* wb = WB0 + ((size_t)ntl*16*64 + l)*8;
    #pragma unroll
    for (int ks = 0; ks < 16; ++ks) wf[ks] = *(const s16x8*)(wb + (size_t)ks*512);
  } else {
    const u16* wb = WB1 + ((size_t)ntl*32*64 + l)*8;
    #pragma unroll
    for (int ks = 0; ks < 32; ++ks) wf[ks] = *(const s16x8*)(wb + (size_t)ks*512);
  }
  const float bv = (w < 4) ? b0p[ntl*16 + lrow] : b1p[ntl*16 + lrow];
  float xw0 = 0.f, xw1 = 0.f, xw2 = 0.f, xw3 = 0.f;
  if (w < 4) {
    xw0 = wx0e[0*NG + ntl*16 + lrow]; xw1 = wx0e[1*NG + ntl*16 + lrow];
    xw2 = wx0e[2*NG + ntl*16 + lrow]; xw3 = wx0e[3*NG + ntl*16 + lrow];
  }

  for (int n = 0; n <= SS; ++n) {
    if (w < 4) {        // ---- layer 0: t = n ----
      if (n < SS) {
        const int t = n;
        f32x4 acc = {0.f, 0.f, 0.f, 0.f};
        if (t > 0) {
          const u16* hb = h1 + (size_t)(t - 1)*65536 + laneoff;
          #pragma unroll
          for (int ks = 0; ks < 16; ++ks) {
            s16x8 a = *(const s16x8*)(hb + (size_t)ks*4096);
            acc = __builtin_amdgcn_mfma_f32_16x16x32_bf16(a, wf[ks], acc, 0, 0, 0);
          }
        }
        #pragma unroll
        for (int r = 0; r < 4; ++r) {
          const int brow = r0 + lg*4 + r;
          const float4 xv = *(const float4*)&x[((size_t)brow*SS + t)*4];
          gs[w][lg*4 + r][lrow] = acc[r] + bv
            + xv.x*xw0 + xv.y*xw1 + xv.z*xw2 + xv.w*xw3;
        }
        if (l < 32) {   // wave-synchronous transpose + paired cell update
          const int row = l >> 1, cp = l & 1;
          const int c0 = cp*2, c1 = cp*2 + 1;
          const float i0 = fsig (gs[w][row][0*4 + c0]);
          const float i1 = fsig (gs[w][row][0*4 + c1]);
          const float f0 = fsig (gs[w][row][1*4 + c0]);
          const float f1 = fsig (gs[w][row][1*4 + c1]);
          const float g0 = ftanh(gs[w][row][2*4 + c0]);
          const float g1 = ftanh(gs[w][row][2*4 + c1]);
          const float o0 = fsig (gs[w][row][3*4 + c0]);
          const float o1 = fsig (gs[w][row][3*4 + c1]);
          creg0 = f0*creg0 + i0*g0;
          creg1 = f1*creg1 + i1*g1;
          stg[0][row][(w & 3)*2 + cp] = (u32)f2bf(o0*ftanh(creg0))
                                      | ((u32)f2bf(o1*ftanh(creg1)) << 16);
        }
      }
    } else {            // ---- layer 1: t = n-1 ----
      if (n >= 1) {
        const int t = n - 1;
        f32x4 acc = {0.f, 0.f, 0.f, 0.f};
        {
          const u16* hb1 = h1 + (size_t)t*65536 + laneoff;
          #pragma unroll
          for (int ks = 0; ks < 16; ++ks) {
            s16x8 a = *(const s16x8*)(hb1 + (size_t)ks*4096);
            acc = __builtin_amdgcn_mfma_f32_16x16x32_bf16(a, wf[ks], acc, 0, 0, 0);
          }
        }
        if (t > 0) {
          const u16* hb2 = h2 + (size_t)(t - 1)*65536 + laneoff;
          #pragma unroll
          for (int ks = 0; ks < 16; ++ks) {
            s16x8 a = *(const s16x8*)(hb2 + (size_t)ks*4096);
            acc = __builtin_amdgcn_mfma_f32_16x16x32_bf16(a, wf[16 + ks], acc, 0, 0, 0);
          }
        }
        #pragma unroll
        for (int r = 0; r < 4; ++r)
          gs[w][lg*4 + r][lrow] = acc[r] + bv;
        if (l < 32) {
          const int row = l >> 1, cp = l & 1;
          const int c0 = cp*2, c1 = cp*2 + 1;
          const float i0 = fsig (gs[w][row][0*4 + c0]);
          const float i1 = fsig (gs[w][row][0*4 + c1]);
          const float f0 = fsig (gs[w][row][1*4 + c0]);
          const float f1 = fsig (gs[w][row][1*4 + c1]);
          const float g0 = ftanh(gs[w][row][2*4 + c0]);
          const float g1 = ftanh(gs[w][row][2*4 + c1]);
          const float o0 = fsig (gs[w][row][3*4 + c0]);
          const float o1 = fsig (gs[w][row][3*4 + c1]);
          creg0 = f0*creg0 + i0*g0;
          creg1 = f1*creg1 + i1*g1;
          stg[1][row][(w & 3)*2 + cp] = (u32)f2bf(o0*ftanh(creg0))
                                      | ((u32)f2bf(o1*ftanh(creg1)) << 16);
        }
      }
    }
    __syncthreads();    // stg complete across all waves
    if (w == 0) {       // wave 0 publishes BOTH layers; lane-consecutive addrs
      if (l < 32) {
        if (n < SS) {
          const int row = l >> 1, half = l & 1;
          const uint4 v = *(uint4*)&stg[0][row][half*4];
          u16* p = h1 + ((size_t)n*32 + j2)*2048 + (size_t)(r0 + row)*16 + half*8;
          st8((u64*)p,     ((u64)v.y << 32) | v.x);
          st8((u64*)p + 1, ((u64)v.w << 32) | v.z);
        }
      } else {
        if (n >= 1) {
          const int row = (l - 32) >> 1, half = l & 1;
          const uint4 v = *(uint4*)&stg[1][row][half*4];
          u16* p = h2 + ((size_t)(n - 1)*32 + j2)*2048 + (size_t)(r0 + row)*16 + half*8;
          st8((u64*)p,     ((u64)v.y << 32) | v.x);
          st8((u64*)p + 1, ((u64)v.w << 32) | v.z);
        }
      }
      asm volatile("s_waitcnt vmcnt(0)" ::: "memory");   // h stores at LLC
      if (n < SS) {
        const u32 tgt = (u32)n + 1u;
        if (l == 0) st4(&flags[j2], tgt);
        if (l < 32) {
          while (ldf(&flags[l]) < tgt) __builtin_amdgcn_s_sleep(1);
        }
      }
    }
    __syncthreads();
    asm volatile("" ::: "memory");   // no hoisting reads above the barrier
  }
}

// ---------------- head: projected = h2flat @ Wp + bp ----------------
// h2 layout [t][j2][b][16]; logical flat row fr = t*BB + b, k-order identity.
__global__ __launch_bounds__(256)
void k_proj(const u16* __restrict__ h2, const float* __restrict__ Wp,
            const float* __restrict__ bp, float* __restrict__ proj)
{
  __shared__ float hsh[8][512];
  const int tid = threadIdx.x;
  const int j   = tid & 127;
  const int rh  = tid >> 7;
  const size_t fr0 = (size_t)blockIdx.x * 8;
  for (int f = tid*8; f < 8*512; f += 2048) {
    const int lr = f >> 9, lc = f & 511;
    const size_t fr = fr0 + lr;
    const int tt = (int)(fr >> 7), bb2 = (int)(fr & 127);
    const u16* src = h2 + (size_t)tt*65536 + (size_t)(lc >> 4)*2048
                   + (size_t)bb2*16 + (lc & 15);
    u16x8 rv = *(const u16x8*)src;
    float4 a, b;
    a.x=bf2f(rv[0]); a.y=bf2f(rv[1]); a.z=bf2f(rv[2]); a.w=bf2f(rv[3]);
    b.x=bf2f(rv[4]); b.y=bf2f(rv[5]); b.z=bf2f(rv[6]); b.w=bf2f(rv[7]);
    *(float4*)&hsh[lr][lc]   = a;
    *(float4*)&hsh[lr][lc+4] = b;
  }
  __syncthreads();
  const float bv = bp[j];
  float a0=bv, a1=bv, a2=bv, a3=bv;
  #pragma unroll 2
  for (int kk = 0; kk < 512; kk += 4) {
    const float w0 = Wp[(size_t)(kk+0)*HH + j];
    const float w1 = Wp[(size_t)(kk+1)*HH + j];
    const float w2 = Wp[(size_t)(kk+2)*HH + j];
    const float w3 = Wp[(size_t)(kk+3)*HH + j];
    const float4 h0 = *(const float4*)&hsh[rh*4+0][kk];
    const float4 h1 = *(const float4*)&hsh[rh*4+1][kk];
    const float4 h2v= *(const float4*)&hsh[rh*4+2][kk];
    const float4 h3 = *(const float4*)&hsh[rh*4+3][kk];
    a0 += h0.x*w0  + h0.y*w1  + h0.z*w2  + h0.w*w3;
    a1 += h1.x*w0  + h1.y*w1  + h1.z*w2  + h1.w*w3;
    a2 += h2v.x*w0 + h2v.y*w1 + h2v.z*w2 + h2v.w*w3;
    a3 += h3.x*w0  + h3.y*w1  + h3.z*w2  + h3.w*w3;
  }
  #pragma unroll
  for (int q = 0; q < 4; ++q) {
    const size_t fr = fr0 + rh*4 + q;
    const int bb = (int)(fr & 127);
    const int ss2 = (int)(fr >> 7);
    const float v = (q == 0) ? a0 : (q == 1) ? a1 : (q == 2) ? a2 : a3;
    proj[((size_t)bb*SS + ss2)*HH + j] = v;
  }
}

// ---------------- head: scores = tanh(proj @ Wa + ba) @ va ----------------
__global__ __launch_bounds__(256)
void k_scores(const float* __restrict__ proj, const float* __restrict__ Wa,
              const float* __restrict__ ba, const float* __restrict__ va,
              float* __restrict__ scores)
{
  __shared__ float was[64*128];
  __shared__ float ps[32][128];
  __shared__ float red[4];
  const int tid = threadIdx.x;
  const size_t bs0 = (size_t)blockIdx.x * 32;
  for (int f = tid*4; f < 32*128; f += 1024) {
    const int lr = f >> 7, lc = f & 127;
    *(float4*)&ps[lr][lc] = *(const float4*)&proj[(bs0 + lr)*HH + lc];
  }
  const int j  = tid & 127;
  const int rh = tid >> 7;
  float yacc[16];
  const float bav = ba[j];
  #pragma unroll
  for (int rp = 0; rp < 16; ++rp) yacc[rp] = bav;
  for (int half = 0; half < 2; ++half) {
    __syncthreads();
    for (int f = tid*4; f < 64*128; f += 1024)
      *(float4*)&was[f] = *(const float4*)&Wa[(size_t)half*8192 + f];
    __syncthreads();
    for (int rp = 0; rp < 16; ++rp) {
      const int rrow = rp*2 + rh;
      float y = yacc[rp];
      #pragma unroll 8
      for (int i2 = 0; i2 < 64; ++i2)
        y += ps[rrow][half*64 + i2] * was[i2*128 + j];
      yacc[rp] = y;
    }
  }
  const float vav = va[j];
  for (int rp = 0; rp < 16; ++rp) {
    float y = ftanh(yacc[rp]) * vav;
    for (int off = 32; off > 0; off >>= 1) y += __shfl_down(y, off);
    __syncthreads();
    if ((tid & 63) == 0) red[tid >> 6] = y;
    __syncthreads();
    if (tid == 0) scores[bs0 + rp*2 + 0] = red[0] + red[1];
    if (tid == 1) scores[bs0 + rp*2 + 1] = red[2] + red[3];
  }
}

// ---------------- head: softmax + context + output ----------------
__global__ __launch_bounds__(256)
void k_final(const float* __restrict__ proj, const float* __restrict__ scores,
             const float* __restrict__ Wo, const float* __restrict__ bo,
             float* __restrict__ out)
{
  __shared__ float sc[512];
  __shared__ float red[4];
  __shared__ float ctx2[2][128];
  const int tid = threadIdx.x;
  const int b = blockIdx.x;
  *(float2*)&sc[tid*2] = *(const float2*)&scores[(size_t)b*SS + tid*2];
  __syncthreads();
  float m = fmaxf(sc[tid], sc[tid+256]);
  for (int off = 32; off > 0; off >>= 1) m = fmaxf(m, __shfl_down(m, off));
  if ((tid & 63) == 0) red[tid >> 6] = m;
  __syncthreads();
  const float M = fmaxf(fmaxf(red[0], red[1]), fmaxf(red[2], red[3]));
  __syncthreads();
  const float e0 = __expf(sc[tid]     - M);
  const float e1 = __expf(sc[tid+256] - M);
  sc[tid] = e0; sc[tid+256] = e1;
  float s = e0 + e1;
  for (int off = 32; off > 0; off >>= 1) s += __shfl_down(s, off);
  if ((tid & 63) == 0) red[tid >> 6] = s;
  __syncthreads();
  const float rinv = 1.f/(red[0] + red[1] + red[2] + red[3]);
  const int h  = tid & 127;
  const int sh = tid >> 7;
  float cp = 0.f;
  #pragma unroll 4
  for (int ssi = sh*256; ssi < sh*256 + 256; ++ssi)
    cp += sc[ssi]*proj[((size_t)b*SS + ssi)*HH + h];
  ctx2[sh][h] = cp;
  __syncthreads();
  if (tid < 128) {
    const float ctx = (ctx2[0][tid] + ctx2[1][tid])*rinv;
    float v = ctx*Wo[tid];
    for (int off = 32; off > 0; off >>= 1) v += __shfl_down(v, off);
    if ((tid & 63) == 0) red[tid >> 6] = v;
  }
  __syncthreads();
  if (tid == 0) out[b] = red[0] + red[1] + bo[0];
}

// ---------------- host ----------------
extern "C" void kernel_launch(void* const* d_in, const int* in_sizes, int n_in,
                              void* d_out, int out_size, void* d_ws, size_t ws_size,
                              hipStream_t stream)
{
  (void)in_sizes; (void)n_in; (void)out_size;
  const float* x   = (const float*)d_in[0];
  const float* Wx0 = (const float*)d_in[1];
  const float* Wh0 = (const float*)d_in[2];
  const float* b0  = (const float*)d_in[3];
  const float* Wx1 = (const float*)d_in[4];
  const float* Wh1 = (const float*)d_in[5];
  const float* b1  = (const float*)d_in[6];
  const float* Wp  = (const float*)d_in[7];
  const float* bp  = (const float*)d_in[8];
  const float* Wa  = (const float*)d_in[9];
  const float* ba  = (const float*)d_in[10];
  const float* va  = (const float*)d_in[11];
  const float* Wo  = (const float*)d_in[12];
  const float* bo  = (const float*)d_in[13];
  float* ws  = (float*)d_ws;
  u16*   wsu = (u16*)((char*)d_ws + F_END*4);

  if (ws_size < NEED_BYTES) {
    fprintf(stderr, "[qnn] ws too small: have=%zu need=%zu\n", ws_size, NEED_BYTES);
    return;
  }

  k_expand<<<8192, 256, 0, stream>>>(Wh0, Wx1, Wh1, Wx0, b0, b1,
                                     wsu + U_WB0, wsu + U_WB1,
                                     ws + F_WX0E, ws + F_B0P, ws + F_B1P);
  k_init<<<2, 256, 0, stream>>>((u32*)(ws + F_BAR));

  k_lstm<<<256, 512, 0, stream>>>(wsu + U_WB0, wsu + U_WB1,
                                  ws + F_B0P, ws + F_B1P, ws + F_WX0E, x,
                                  wsu + U_H1, wsu + U_H2,
                                  (u32*)(ws + F_BAR));

  k_proj  <<<BB*SS/8,  256, 0, stream>>>(wsu + U_H2, Wp, bp, ws + F_PROJ);
  k_scores<<<BB*SS/32, 256, 0, stream>>>(ws + F_PROJ, Wa, ba, va, ws + F_SCORE);
  k_final <<<BB,       256, 0, stream>>>(ws + F_PROJ, ws + F_SCORE, Wo, bo,
                                         (float*)d_out);
}

// Round 13
// 2615.554 us; speedup vs baseline: 8.4165x; 1.3401x over previous
//
#include <hip/hip_runtime.h>
#include <cstdio>
#include <cstddef>

#define BB 128
#define SS 512
#define HH 128
#define NG 2048   // 4H*4 components, permuted column layout n' = m*16 + g*4 + co

typedef unsigned short u16;
typedef unsigned int   u32;
typedef __attribute__((ext_vector_type(8))) u16   u16x8;
typedef __attribute__((ext_vector_type(8))) short s16x8;
typedef __attribute__((ext_vector_type(4))) float f32x4;
typedef __attribute__((ext_vector_type(4))) u32   u32x4;

__constant__ int   c_widx[16] = {0,1,2,3, 1,0,3,2, 2,3,0,1, 3,2,1,0};
__constant__ float c_sgn [16] = {1.f,1.f,1.f,1.f, -1.f,1.f,-1.f,1.f,
                                 -1.f,1.f,1.f,-1.f, -1.f,-1.f,1.f,1.f};

__device__ __forceinline__ float fsig(float x) { return 1.f/(1.f + __expf(-x)); }
__device__ __forceinline__ float ftanh(float x) {
  float ax = fabsf(x);
  float e  = __expf(-2.f*ax);
  float tt = (1.f - e)/(1.f + e);
  return copysignf(tt, x);
}
__device__ __forceinline__ float bf2f(u16 u) {
  return __uint_as_float(((unsigned)u) << 16);
}
__device__ __forceinline__ u16 f2bf(float f) {  // round-to-nearest-even
  unsigned u = __float_as_uint(f);
  return (u16)((u + 0x7fffu + ((u >> 16) & 1u)) >> 16);
}

// sc1 (device-scope write-through, bypasses the non-coherent per-XCD L2) —
// the R6/R7/R9/R11-validated protocol. Reads of h use PLAIN cached loads:
// every h address is fresh-per-dispatch (kernel-boundary acquire invalidates
// caches), so reader caches can't be stale; misses pull the sc1 truth.
__device__ __forceinline__ void st4(u32* p, u32 v) {
  __hip_atomic_store(p, v, __ATOMIC_RELAXED, __HIP_MEMORY_SCOPE_AGENT);
}
__device__ __forceinline__ u32 ldf(const u32* p) {
  return __hip_atomic_load(p, __ATOMIC_RELAXED, __HIP_MEMORY_SCOPE_AGENT);
}
// 16B device-scope write-through store (full-sector coalescing, 1 msg/lane).
// Operand must be a NATIVE vector type for the "v" constraint (R12 lesson:
// HIP's uint4 struct fails with "indirect register inputs").
__device__ __forceinline__ void st16_sc1(void* p, u32x4 v) {
  asm volatile("global_store_dwordx4 %0, %1, off sc1"
               :: "v"(p), "v"(v) : "memory");
}

// ---------------- workspace layout ----------------
constexpr size_t F_B0P  = 0;                               // 2048
constexpr size_t F_B1P  = F_B0P  + 2048;                   // 2048
constexpr size_t F_WX0E = F_B1P  + 2048;                   // 4*2048
constexpr size_t F_PROJ = F_WX0E + 8192;                   // B*S*128
constexpr size_t F_SCORE= F_PROJ + (size_t)BB*SS*HH;       // B*S
constexpr size_t F_BAR  = F_SCORE+ (size_t)BB*SS;          // 8 groups x 32 flags
constexpr size_t F_END  = F_BAR  + 512;
// u16 region, starts at byte F_END*4:
constexpr size_t U_WB0  = 0;                               // 128*16*64*8
constexpr size_t U_WB1  = U_WB0 + (size_t)128*16*64*8;     // 128*32*64*8
constexpr size_t U_H1   = U_WB1 + (size_t)128*32*64*8;     // [t][j2][b][16]
constexpr size_t U_H2   = U_H1  + (size_t)BB*SS*512;
constexpr size_t U_END  = U_H2  + (size_t)BB*SS*512;
constexpr size_t NEED_BYTES = F_END*4 + U_END*2;
// h address (u16 units): t*65536 + (k>>4)*2048 + b*16 + (k&15), k = m*4+co

// ---------------- weight expansion into bf16 fragment-major ----------------
// WB[nt][ks][lane][e]: element W[k = ks*32 + (lane>>4)*8 + e][n' = nt*16 + (lane&15)]
__global__ __launch_bounds__(256)
void k_expand(const float* __restrict__ Wh0, const float* __restrict__ Wx1,
              const float* __restrict__ Wh1, const float* __restrict__ Wx0,
              const float* __restrict__ b0,  const float* __restrict__ b1,
              u16* __restrict__ WB0, u16* __restrict__ WB1,
              float* __restrict__ wx0e, float* __restrict__ b0p,
              float* __restrict__ b1p)
{
  const int idx = blockIdx.x*256 + threadIdx.x;   // 0 .. 2M-1 exactly
  { // WB1 (layer 1, K=1024: rows 0..511 = Wx1 on h1_t, 512..1023 = Wh1)
    const int e  = idx & 7;
    const int ln = (idx >> 3) & 63;
    const int ks = (idx >> 9) & 31;
    const int nt = idx >> 14;
    const int k  = ks*32 + (ln >> 4)*8 + e;
    const int np = nt*16 + (ln & 15);
    const int g  = (np >> 2) & 3, co = np & 3;
    const int o  = g*HH + nt;
    const int ci = k & 3;
    const int wi = c_widx[ci*4+co];
    const float sg = c_sgn[ci*4+co];
    const float wv = (k < 512)
      ? Wx1[((size_t)wi*HH + (k >> 2))*512 + o]
      : Wh1[((size_t)wi*HH + ((k - 512) >> 2))*512 + o];
    WB1[idx] = f2bf(sg*wv);
  }
  if (idx < 128*16*64*8) { // WB0 (layer 0 recurrent, K=512)
    const int e  = idx & 7;
    const int ln = (idx >> 3) & 63;
    const int ks = (idx >> 9) & 15;
    const int nt = idx >> 13;
    const int k  = ks*32 + (ln >> 4)*8 + e;
    const int np = nt*16 + (ln & 15);
    const int g  = (np >> 2) & 3, co = np & 3;
    const int o  = g*HH + nt;
    const int ci = k & 3;
    const int wi = c_widx[ci*4+co];
    const float sg = c_sgn[ci*4+co];
    WB0[idx] = f2bf(sg*Wh0[((size_t)wi*HH + (k >> 2))*512 + o]);
  }
  if (idx < 8192) { // wx0e[ci][n'] fp32 (layer-0 input proj, in=1)
    const int ci = idx >> 11, np = idx & 2047;
    const int m = np >> 4, g = (np >> 2) & 3, co = np & 3;
    const int o = g*HH + m;
    wx0e[idx] = c_sgn[ci*4+co]*Wx0[(size_t)c_widx[ci*4+co]*512 + o];
  }
  if (idx < 2048) { // permuted biases fp32
    const int np = idx;
    const int m = np >> 4, g = (np >> 2) & 3, co = np & 3;
    const int o = g*HH + m;
    b0p[idx] = b0[(size_t)o*4 + co];
    b1p[idx] = b1[(size_t)o*4 + co];
  }
}

__global__ __launch_bounds__(256)
void k_init(u32* __restrict__ bar)
{
  const int i = blockIdx.x*256 + threadIdx.x;
  if (i < 512) bar[i] = 0u;
}

// ---------------- persistent fused 2-layer LSTM ----------------
// 256 blocks x 512 threads (8 waves). Group = bid&7 (32 blocks sharing batch
// rows r0=grp*16). h layout [t][j2][b][16]: each block's per-step output =
// 512B contiguous, exclusively owned. Waves 0-3: layer0 t=n; waves 4-7:
// layer1 t=n-1 (pipelined). Wave 0 publishes both layers with lane-
// consecutive 16B sc1 stores, then stores its flag and polls all 32 group
// flags in parallel. (Validated flag protocol; placement-independent.)
__global__ __launch_bounds__(512, 1)
void k_lstm(const u16* __restrict__ WB0, const u16* __restrict__ WB1,
            const float* __restrict__ b0p, const float* __restrict__ b1p,
            const float* __restrict__ wx0e, const float* __restrict__ x,
            u16* __restrict__ h1, u16* __restrict__ h2,
            u32* __restrict__ bar)
{
  __shared__ float gs[8][16][17];
  __shared__ u16   stg[2][16][16];
  const int tid = threadIdx.x;
  const int bid = blockIdx.x;
  const int grp = bid & 7;           // r0-tile group
  const int j2  = bid >> 3;          // k-slice 0..31 = barrier slot
  const int r0  = grp*16;
  u32* flags = bar + grp*32;         // one 128B line per group

  const int w    = tid >> 6;         // wave 0..7
  const int l    = tid & 63;
  const int lrow = l & 15;
  const int lg   = l >> 4;
  // A-fragment address component for k = ks*32 + lg*8 + e in [t][j2][b][16]:
  const size_t laneoff = (size_t)(lg >> 1)*2048 + (size_t)(r0 + lrow)*16
                       + (size_t)(lg & 1)*8;
  const int ntl = j2*4 + (w & 3);
  const int erow = l >> 2, eco = l & 3;   // epilogue: 1 comp per lane
  float creg = 0.f;

  s16x8 wf[32];
  if (w < 4) {
    const u16* wb = WB0 + ((size_t)ntl*16*64 + l)*8;
    #pragma unroll
    for (int ks = 0; ks < 16; ++ks) wf[ks] = *(const s16x8*)(wb + (size_t)ks*512);
  } else {
    const u16* wb = WB1 + ((size_t)ntl*32*64 + l)*8;
    #pragma unroll
    for (int ks = 0; ks < 32; ++ks) wf[ks] = *(const s16x8*)(wb + (size_t)ks*512);
  }
  const float bv = (w < 4) ? b0p[ntl*16 + lrow] : b1p[ntl*16 + lrow];
  float xw0 = 0.f, xw1 = 0.f, xw2 = 0.f, xw3 = 0.f;
  if (w < 4) {
    xw0 = wx0e[0*NG + ntl*16 + lrow]; xw1 = wx0e[1*NG + ntl*16 + lrow];
    xw2 = wx0e[2*NG + ntl*16 + lrow]; xw3 = wx0e[3*NG + ntl*16 + lrow];
  }

  for (int n = 0; n <= SS; ++n) {
    if (w < 4) {        // ---- layer 0: t = n ----
      if (n < SS) {
        const int t = n;
        f32x4 acc = {0.f, 0.f, 0.f, 0.f};
        if (t > 0) {
          const u16* hb = h1 + (size_t)(t - 1)*65536 + laneoff;
          #pragma unroll
          for (int ks = 0; ks < 16; ++ks) {
            s16x8 a = *(const s16x8*)(hb + (size_t)ks*4096);
            acc = __builtin_amdgcn_mfma_f32_16x16x32_bf16(a, wf[ks], acc, 0, 0, 0);
          }
        }
        #pragma unroll
        for (int r = 0; r < 4; ++r) {
          const int brow = r0 + lg*4 + r;
          const float4 xv = *(const float4*)&x[((size_t)brow*SS + t)*4];
          gs[w][lg*4 + r][lrow] = acc[r] + bv
            + xv.x*xw0 + xv.y*xw1 + xv.z*xw2 + xv.w*xw3;
        }
        // wave-synchronous transpose + cell update: 1 component per lane
        {
          const float i_g = fsig (gs[w][erow][0*4 + eco]);
          const float f_g = fsig (gs[w][erow][1*4 + eco]);
          const float g_g = ftanh(gs[w][erow][2*4 + eco]);
          const float o_g = fsig (gs[w][erow][3*4 + eco]);
          creg = f_g*creg + i_g*g_g;
          stg[0][erow][(w & 3)*4 + eco] = f2bf(o_g*ftanh(creg));
        }
      }
    } else {            // ---- layer 1: t = n-1 ----
      if (n >= 1) {
        const int t = n - 1;
        f32x4 acc = {0.f, 0.f, 0.f, 0.f};
        {
          const u16* hb1 = h1 + (size_t)t*65536 + laneoff;
          #pragma unroll
          for (int ks = 0; ks < 16; ++ks) {
            s16x8 a = *(const s16x8*)(hb1 + (size_t)ks*4096);
            acc = __builtin_amdgcn_mfma_f32_16x16x32_bf16(a, wf[ks], acc, 0, 0, 0);
          }
        }
        if (t > 0) {
          const u16* hb2 = h2 + (size_t)(t - 1)*65536 + laneoff;
          #pragma unroll
          for (int ks = 0; ks < 16; ++ks) {
            s16x8 a = *(const s16x8*)(hb2 + (size_t)ks*4096);
            acc = __builtin_amdgcn_mfma_f32_16x16x32_bf16(a, wf[16 + ks], acc, 0, 0, 0);
          }
        }
        #pragma unroll
        for (int r = 0; r < 4; ++r)
          gs[w][lg*4 + r][lrow] = acc[r] + bv;
        {
          const float i_g = fsig (gs[w][erow][0*4 + eco]);
          const float f_g = fsig (gs[w][erow][1*4 + eco]);
          const float g_g = ftanh(gs[w][erow][2*4 + eco]);
          const float o_g = fsig (gs[w][erow][3*4 + eco]);
          creg = f_g*creg + i_g*g_g;
          stg[1][erow][(w & 3)*4 + eco] = f2bf(o_g*ftanh(creg));
        }
      }
    }
    __syncthreads();    // stg complete across all waves
    if (w == 0) {       // wave 0 publishes BOTH layers; 16B per lane, coalesced
      if (l < 32) {
        if (n < SS) {
          const int row = l >> 1, half = l & 1;
          u16* p = h1 + ((size_t)n*32 + j2)*2048 + (size_t)(r0 + row)*16 + half*8;
          st16_sc1(p, *(const u32x4*)&stg[0][row][half*8]);
        }
      } else {
        if (n >= 1) {
          const int ll = l - 32;
          const int row = ll >> 1, half = ll & 1;
          u16* p = h2 + ((size_t)(n - 1)*32 + j2)*2048 + (size_t)(r0 + row)*16 + half*8;
          st16_sc1(p, *(const u32x4*)&stg[1][row][half*8]);
        }
      }
      asm volatile("s_waitcnt vmcnt(0)" ::: "memory");   // h stores at LLC
      if (n < SS) {
        const u32 tgt = (u32)n + 1u;
        if (l == 0) st4(&flags[j2], tgt);
        if (l < 32) {
          while (ldf(&flags[l]) < tgt) __builtin_amdgcn_s_sleep(1);
        }
      }
    }
    __syncthreads();
    asm volatile("" ::: "memory");   // no hoisting reads above the barrier
  }
}

// ---------------- head: projected = h2flat @ Wp + bp ----------------
// h2 layout [t][j2][b][16]; logical flat row fr = t*BB + b, k-order identity.
__global__ __launch_bounds__(256)
void k_proj(const u16* __restrict__ h2, const float* __restrict__ Wp,
            const float* __restrict__ bp, float* __restrict__ proj)
{
  __shared__ float hsh[8][512];
  const int tid = threadIdx.x;
  const int j   = tid & 127;
  const int rh  = tid >> 7;
  const size_t fr0 = (size_t)blockIdx.x * 8;
  for (int f = tid*8; f < 8*512; f += 2048) {
    const int lr = f >> 9, lc = f & 511;
    const size_t fr = fr0 + lr;
    const int tt = (int)(fr >> 7), bb2 = (int)(fr & 127);
    const u16* src = h2 + (size_t)tt*65536 + (size_t)(lc >> 4)*2048
                   + (size_t)bb2*16 + (lc & 15);
    u16x8 rv = *(const u16x8*)src;
    float4 a, b;
    a.x=bf2f(rv[0]); a.y=bf2f(rv[1]); a.z=bf2f(rv[2]); a.w=bf2f(rv[3]);
    b.x=bf2f(rv[4]); b.y=bf2f(rv[5]); b.z=bf2f(rv[6]); b.w=bf2f(rv[7]);
    *(float4*)&hsh[lr][lc]   = a;
    *(float4*)&hsh[lr][lc+4] = b;
  }
  __syncthreads();
  const float bv = bp[j];
  float a0=bv, a1=bv, a2=bv, a3=bv;
  #pragma unroll 2
  for (int kk = 0; kk < 512; kk += 4) {
    const float w0 = Wp[(size_t)(kk+0)*HH + j];
    const float w1 = Wp[(size_t)(kk+1)*HH + j];
    const float w2 = Wp[(size_t)(kk+2)*HH + j];
    const float w3 = Wp[(size_t)(kk+3)*HH + j];
    const float4 h0 = *(const float4*)&hsh[rh*4+0][kk];
    const float4 h1 = *(const float4*)&hsh[rh*4+1][kk];
    const float4 h2v= *(const float4*)&hsh[rh*4+2][kk];
    const float4 h3 = *(const float4*)&hsh[rh*4+3][kk];
    a0 += h0.x*w0  + h0.y*w1  + h0.z*w2  + h0.w*w3;
    a1 += h1.x*w0  + h1.y*w1  + h1.z*w2  + h1.w*w3;
    a2 += h2v.x*w0 + h2v.y*w1 + h2v.z*w2 + h2v.w*w3;
    a3 += h3.x*w0  + h3.y*w1  + h3.z*w2  + h3.w*w3;
  }
  #pragma unroll
  for (int q = 0; q < 4; ++q) {
    const size_t fr = fr0 + rh*4 + q;
    const int bb = (int)(fr & 127);
    const int ss2 = (int)(fr >> 7);
    const float v = (q == 0) ? a0 : (q == 1) ? a1 : (q == 2) ? a2 : a3;
    proj[((size_t)bb*SS + ss2)*HH + j] = v;
  }
}

// ---------------- head: scores = tanh(proj @ Wa + ba) @ va ----------------
__global__ __launch_bounds__(256)
void k_scores(const float* __restrict__ proj, const float* __restrict__ Wa,
              const float* __restrict__ ba, const float* __restrict__ va,
              float* __restrict__ scores)
{
  __shared__ float was[64*128];
  __shared__ float ps[32][128];
  __shared__ float red[4];
  const int tid = threadIdx.x;
  const size_t bs0 = (size_t)blockIdx.x * 32;
  for (int f = tid*4; f < 32*128; f += 1024) {
    const int lr = f >> 7, lc = f & 127;
    *(float4*)&ps[lr][lc] = *(const float4*)&proj[(bs0 + lr)*HH + lc];
  }
  const int j  = tid & 127;
  const int rh = tid >> 7;
  float yacc[16];
  const float bav = ba[j];
  #pragma unroll
  for (int rp = 0; rp < 16; ++rp) yacc[rp] = bav;
  for (int half = 0; half < 2; ++half) {
    __syncthreads();
    for (int f = tid*4; f < 64*128; f += 1024)
      *(float4*)&was[f] = *(const float4*)&Wa[(size_t)half*8192 + f];
    __syncthreads();
    for (int rp = 0; rp < 16; ++rp) {
      const int rrow = rp*2 + rh;
      float y = yacc[rp];
      #pragma unroll 8
      for (int i2 = 0; i2 < 64; ++i2)
        y += ps[rrow][half*64 + i2] * was[i2*128 + j];
      yacc[rp] = y;
    }
  }
  const float vav = va[j];
  for (int rp = 0; rp < 16; ++rp) {
    float y = ftanh(yacc[rp]) * vav;
    for (int off = 32; off > 0; off >>= 1) y += __shfl_down(y, off);
    __syncthreads();
    if ((tid & 63) == 0) red[tid >> 6] = y;
    __syncthreads();
    if (tid == 0) scores[bs0 + rp*2 + 0] = red[0] + red[1];
    if (tid == 1) scores[bs0 + rp*2 + 1] = red[2] + red[3];
  }
}

// ---------------- head: softmax + context + output ----------------
__global__ __launch_bounds__(256)
void k_final(const float* __restrict__ proj, const float* __restrict__ scores,
             const float* __restrict__ Wo, const float* __restrict__ bo,
             float* __restrict__ out)
{
  __shared__ float sc[512];
  __shared__ float red[4];
  __shared__ float ctx2[2][128];
  const int tid = threadIdx.x;
  const int b = blockIdx.x;
  *(float2*)&sc[tid*2] = *(const float2*)&scores[(size_t)b*SS + tid*2];
  __syncthreads();
  float m = fmaxf(sc[tid], sc[tid+256]);
  for (int off = 32; off > 0; off >>= 1) m = fmaxf(m, __shfl_down(m, off));
  if ((tid & 63) == 0) red[tid >> 6] = m;
  __syncthreads();
  const float M = fmaxf(fmaxf(red[0], red[1]), fmaxf(red[2], red[3]));
  __syncthreads();
  const float e0 = __expf(sc[tid]     - M);
  const float e1 = __expf(sc[tid+256] - M);
  sc[tid] = e0; sc[tid+256] = e1;
  float s = e0 + e1;
  for (int off = 32; off > 0; off >>= 1) s += __shfl_down(s, off);
  if ((tid & 63) == 0) red[tid >> 6] = s;
  __syncthreads();
  const float rinv = 1.f/(red[0] + red[1] + red[2] + red[3]);
  const int h  = tid & 127;
  const int sh = tid >> 7;
  float cp = 0.f;
  #pragma unroll 4
  for (int ssi = sh*256; ssi < sh*256 + 256; ++ssi)
    cp += sc[ssi]*proj[((size_t)b*SS + ssi)*HH + h];
  ctx2[sh][h] = cp;
  __syncthreads();
  if (tid < 128) {
    const float ctx = (ctx2[0][tid] + ctx2[1][tid])*rinv;
    float v = ctx*Wo[tid];
    for (int off = 32; off > 0; off >>= 1) v += __shfl_down(v, off);
    if ((tid & 63) == 0) red[tid >> 6] = v;
  }
  __syncthreads();
  if (tid == 0) out[b] = red[0] + red[1] + bo[0];
}

// ---------------- host ----------------
extern "C" void kernel_launch(void* const* d_in, const int* in_sizes, int n_in,
                              void* d_out, int out_size, void* d_ws, size_t ws_size,
                              hipStream_t stream)
{
  (void)in_sizes; (void)n_in; (void)out_size;
  const float* x   = (const float*)d_in[0];
  const float* Wx0 = (const float*)d_in[1];
  const float* Wh0 = (const float*)d_in[2];
  const float* b0  = (const float*)d_in[3];
  const float* Wx1 = (const float*)d_in[4];
  const float* Wh1 = (const float*)d_in[5];
  const float* b1  = (const float*)d_in[6];
  const float* Wp  = (const float*)d_in[7];
  const float* bp  = (const float*)d_in[8];
  const float* Wa  = (const float*)d_in[9];
  const float* ba  = (const float*)d_in[10];
  const float* va  = (const float*)d_in[11];
  const float* Wo  = (const float*)d_in[12];
  const float* bo  = (const float*)d_in[13];
  float* ws  = (float*)d_ws;
  u16*   wsu = (u16*)((char*)d_ws + F_END*4);

  if (ws_size < NEED_BYTES) {
    fprintf(stderr, "[qnn] ws too small: have=%zu need=%zu\n", ws_size, NEED_BYTES);
    return;
  }

  k_expand<<<8192, 256, 0, stream>>>(Wh0, Wx1, Wh1, Wx0, b0, b1,
                                     wsu + U_WB0, wsu + U_WB1,
                                     ws + F_WX0E, ws + F_B0P, ws + F_B1P);
  k_init<<<2, 256, 0, stream>>>((u32*)(ws + F_BAR));

  k_lstm<<<256, 512, 0, stream>>>(wsu + U_WB0, wsu + U_WB1,
                                  ws + F_B0P, ws + F_B1P, ws + F_WX0E, x,
                                  wsu + U_H1, wsu + U_H2,
                                  (u32*)(ws + F_BAR));

  k_proj  <<<BB*SS/8,  256, 0, stream>>>(wsu + U_H2, Wp, bp, ws + F_PROJ);
  k_scores<<<BB*SS/32, 256, 0, stream>>>(ws + F_PROJ, Wa, ba, va, ws + F_SCORE);
  k_final <<<BB,       256, 0, stream>>>(ws + F_PROJ, ws + F_SCORE, Wo, bo,
                                         (float*)d_out);
}